// Round 16
// baseline (260.858 us; speedup 1.0000x reference)
//
#include <hip/hip_runtime.h>
#include <hip/hip_bf16.h>

#define B_ 8
#define N_ 4096
#define D_ 1024

#define AS1 __attribute__((address_space(1)))
#define AS3 __attribute__((address_space(3)))
__device__ __forceinline__ void gld16(const float* g, float* l) {
    __builtin_amdgcn_global_load_lds((const AS1 void*)g, (AS3 void*)l, 16, 0, 0);
}

// ---------------------------------------------------------------------------
// K0: prep. blocks 0..15: qk[r] = (l2norm(layernorm(phi[r]*qg+qb))) ⊙ kg,
//                         cj[r] = Σ q·kb.   block 16: w2=kg², w1=2kg·kb, C=Σkb².
// ---------------------------------------------------------------------------
__global__ __launch_bounds__(64) void k_prep(
    const float* __restrict__ phi, const float* __restrict__ qg, const float* __restrict__ qb,
    const float* __restrict__ lng, const float* __restrict__ lnb,
    const float* __restrict__ kg, const float* __restrict__ kb,
    float* __restrict__ qk, float* __restrict__ cj, float* __restrict__ wbuf)
{
    int r = blockIdx.x;        // 0..16
    int lane = threadIdx.x;    // 0..63
    if (r == 16) {
        float cacc = 0.f;
#pragma unroll
        for (int c = 0; c < 16; ++c) {
            int i = c * 64 + lane;
            float g = kg[i], b = kb[i];
            wbuf[i] = g * g;
            wbuf[1024 + i] = 2.0f * g * b;
            cacc += b * b;
        }
#pragma unroll
        for (int m = 32; m; m >>= 1) cacc += __shfl_xor(cacc, m);
        if (lane == 0) wbuf[2048] = cacc;
        return;
    }
    const float* pr = phi + (size_t)r * D_;
    float v[16];
    float s1 = 0.f;
#pragma unroll
    for (int c = 0; c < 16; ++c) {
        int i = c * 64 + lane;
        v[c] = pr[i] * qg[i] + qb[i];
        s1 += v[c];
    }
#pragma unroll
    for (int m = 32; m; m >>= 1) s1 += __shfl_xor(s1, m);
    float mu = s1 * (1.0f / D_);
    float s2 = 0.f;
#pragma unroll
    for (int c = 0; c < 16; ++c) { float dd = v[c] - mu; s2 += dd * dd; }
#pragma unroll
    for (int m = 32; m; m >>= 1) s2 += __shfl_xor(s2, m);
    float var = s2 * (1.0f / D_);
    float inv = 1.0f / sqrtf(var + 1e-5f);
    float u[16];
    float s3 = 0.f;
#pragma unroll
    for (int c = 0; c < 16; ++c) {
        int i = c * 64 + lane;
        u[c] = (v[c] - mu) * inv * lng[i] + lnb[i];
        s3 += u[c] * u[c];
    }
#pragma unroll
    for (int m = 32; m; m >>= 1) s3 += __shfl_xor(s3, m);
    float rn = 1.0f / (sqrtf(s3) + 1e-6f);
    float cacc = 0.f;
#pragma unroll
    for (int c = 0; c < 16; ++c) {
        int i = c * 64 + lane;
        float qv = u[c] * rn;
        qk[(size_t)r * D_ + i] = qv * kg[i];
        cacc += qv * kb[i];
    }
#pragma unroll
    for (int m = 32; m; m >>= 1) cacc += __shfl_xor(cacc, m);
    if (lane == 0) cj[r] = cacc;
}

// ---------------------------------------------------------------------------
// K1: FUSED logits + softmax-dispatch + slot-partials.
// 256 threads/block, 64 tokens/block, 4 tokens/thread (acc[4][17]), 512 blocks.
// CRITICAL (rule #20): the c-reduce p-loop is FULLY UNROLLED so every acc[p][v]
// index is compile-time-constant -> acc stays in VGPRs (round-14/15 had
// `#pragma unroll 1` there: runtime p forced the whole acc array to scratch,
// 104 MB of spill traffic). qk staged in two 32KB d-halves; barrier-free
// dc-loops; each q4 ds_read feeds 16 FMAs. Phase 2: thread owns one d-float4.
// ---------------------------------------------------------------------------
__global__ __launch_bounds__(256, 1) void k_fused(
    const float* __restrict__ x, const float* __restrict__ qk,
    const float* __restrict__ wbuf, const float* __restrict__ cj,
    const float* __restrict__ s0p,
    float* __restrict__ lgbuf, float* __restrict__ spart)
{
    __shared__ float smem[8192];   // 32 KB: qk-half [16][512]; later red|sums|disp
    float* qs   = smem;            // qk[j][dh*512 .. +512) at qs[j*512 ..]
    float* red  = smem;            // 4352 floats (16 tok x 17 v x 16 c)
    float* sums = smem + 4352;     // 1088 (64 tok x 17)
    float* disp = smem + 5440;     // 1024 (64 tok x 16)

    int tid = threadIdx.x;
    int tok0 = blockIdx.x * 64;
    int wid = tid >> 6;            // 0..3
    int r0 = tid >> 4;             // 0..15
    int c4 = (tid & 15) * 4;       // c-slice within 64-float chunk

    float acc[4][17];
#pragma unroll
    for (int i = 0; i < 4; ++i)
#pragma unroll
        for (int v = 0; v < 17; ++v) acc[i][v] = 0.f;

#pragma unroll 1
    for (int dh = 0; dh < 2; ++dh) {
        if (dh) __syncthreads();   // half-0 reads done before restage
        // stage qk half dh: 2048 float4 slots, 8 gld16/thread (linear dest)
#pragma unroll
        for (int i = 0; i < 8; ++i) {
            int s = i * 256 + tid;           // float4 slot = j*128 + col4
            int j = s >> 7;
            int col = (s & 127) * 4;
            gld16(qk + (size_t)j * 1024 + dh * 512 + col,
                  &qs[(i * 256 + wid * 64) * 4]);
        }
        __syncthreads();           // DMA drained by barrier

        // barrier-free dc-loop: thread owns tokens {i*16+r0}, c-slice c4
#pragma unroll 2
        for (int dcl = 0; dcl < 8; ++dcl) {
            int dc = dh * 8 + dcl;
            float4 xv[4];
#pragma unroll
            for (int i = 0; i < 4; ++i)
                xv[i] = *(const float4*)(x + (size_t)(tok0 + i * 16 + r0) * D_ + dc * 64 + c4);
            float4 w2v = *(const float4*)(wbuf + dc * 64 + c4);          // L2 broadcast
            float4 w1v = *(const float4*)(wbuf + 1024 + dc * 64 + c4);
#pragma unroll
            for (int i = 0; i < 4; ++i)
                acc[i][16] += (w2v.x * xv[i].x + w1v.x) * xv[i].x
                            + (w2v.y * xv[i].y + w1v.y) * xv[i].y
                            + (w2v.z * xv[i].z + w1v.z) * xv[i].z
                            + (w2v.w * xv[i].w + w1v.w) * xv[i].w;
            const float* qb = qs + dcl * 64 + c4;
#pragma unroll
            for (int j = 0; j < 16; ++j) {
                float4 q4 = *(const float4*)(qb + j * 512);
#pragma unroll
                for (int i = 0; i < 4; ++i)
                    acc[i][j] += xv[i].x * q4.x + xv[i].y * q4.y
                               + xv[i].z * q4.z + xv[i].w * q4.w;
            }
        }
    }
    __syncthreads();   // all qs reads done before reuse as red

    // ---- c-reduce: 4 quarter-passes of 16 tokens. FULLY UNROLLED p so
    // acc[p][v] indices are static (rule #20: dynamic p -> scratch spill).
#pragma unroll
    for (int p = 0; p < 4; ++p) {
#pragma unroll
        for (int v = 0; v < 17; ++v)
            red[(r0 * 17 + v) * 16 + (tid & 15)] = acc[p][v];
        __syncthreads();
#pragma unroll
        for (int it = 0; it < 2; ++it) {
            int idx = tid + it * 256;
            if (idx < 272) {
                const float4* pp = (const float4*)(red + idx * 16);
                float4 a = pp[0], b = pp[1], cq = pp[2], dq = pp[3];
                float sum = (((a.x + a.y) + (a.z + a.w)) + ((b.x + b.y) + (b.z + b.w)))
                          + (((cq.x + cq.y) + (cq.z + cq.w)) + ((dq.x + dq.y) + (dq.z + dq.w)));
                int t = idx / 17, v = idx - t * 17;
                lgbuf[(size_t)(tok0 + p * 16 + t) * 20 + v] = sum;
                sums[(p * 16 + t) * 17 + v] = sum;
            }
        }
        __syncthreads();
    }

    // ---- softmax-dispatch (entmax in k_epi): one thread per token
    if (tid < 64) {
        const float* sp = sums + tid * 17;
        float ss = sp[16] + wbuf[2048];
        float rn = 1.0f / (sqrtf(ss) + 1e-6f);
        float inv0 = 1.0f / s0p[0];
        float lg[16];
#pragma unroll
        for (int j = 0; j < 16; ++j) lg[j] = (sp[j] + cj[j]) * rn;
        float dsp[16];
#pragma unroll
        for (int sl = 0; sl < 2; ++sl) {
            float a[8], m = -1e30f;
#pragma unroll
            for (int ee = 0; ee < 8; ++ee) { a[ee] = lg[2 * ee + sl] * inv0; m = fmaxf(m, a[ee]); }
            float den = 0.f;
#pragma unroll
            for (int ee = 0; ee < 8; ++ee) { a[ee] = expf(a[ee] - m); den += a[ee]; }
            float r = 1.0f / den;
#pragma unroll
            for (int ee = 0; ee < 8; ++ee) dsp[2 * ee + sl] = a[ee] * r;
        }
#pragma unroll
        for (int q4i = 0; q4i < 4; ++q4i)
            *(float4*)(&disp[tid * 16 + q4i * 4]) =
                make_float4(dsp[q4i * 4 + 0], dsp[q4i * 4 + 1], dsp[q4i * 4 + 2], dsp[q4i * 4 + 3]);
    }
    __syncthreads();

    // ---- phase 2: slot partials; thread owns d-float4, all 16 j.
    const float* xp = x + (size_t)tok0 * D_ + tid * 4;
    float4 acc2[16];
#pragma unroll
    for (int j = 0; j < 16; ++j) { acc2[j].x = 0.f; acc2[j].y = 0.f; acc2[j].z = 0.f; acc2[j].w = 0.f; }
#pragma unroll 4
    for (int n = 0; n < 64; ++n) {
        float4 xv = *(const float4*)(xp + (size_t)n * D_);
        const float4* q4 = (const float4*)(disp + n * 16);
        float4 s0 = q4[0], s1 = q4[1], s2 = q4[2], s3 = q4[3];
        acc2[0].x  += s0.x * xv.x; acc2[0].y  += s0.x * xv.y; acc2[0].z  += s0.x * xv.z; acc2[0].w  += s0.x * xv.w;
        acc2[1].x  += s0.y * xv.x; acc2[1].y  += s0.y * xv.y; acc2[1].z  += s0.y * xv.z; acc2[1].w  += s0.y * xv.w;
        acc2[2].x  += s0.z * xv.x; acc2[2].y  += s0.z * xv.y; acc2[2].z  += s0.z * xv.z; acc2[2].w  += s0.z * xv.w;
        acc2[3].x  += s0.w * xv.x; acc2[3].y  += s0.w * xv.y; acc2[3].z  += s0.w * xv.z; acc2[3].w  += s0.w * xv.w;
        acc2[4].x  += s1.x * xv.x; acc2[4].y  += s1.x * xv.y; acc2[4].z  += s1.x * xv.z; acc2[4].w  += s1.x * xv.w;
        acc2[5].x  += s1.y * xv.x; acc2[5].y  += s1.y * xv.y; acc2[5].z  += s1.y * xv.z; acc2[5].w  += s1.y * xv.w;
        acc2[6].x  += s1.z * xv.x; acc2[6].y  += s1.z * xv.y; acc2[6].z  += s1.z * xv.z; acc2[6].w  += s1.z * xv.w;
        acc2[7].x  += s1.w * xv.x; acc2[7].y  += s1.w * xv.y; acc2[7].z  += s1.w * xv.z; acc2[7].w  += s1.w * xv.w;
        acc2[8].x  += s2.x * xv.x; acc2[8].y  += s2.x * xv.y; acc2[8].z  += s2.x * xv.z; acc2[8].w  += s2.x * xv.w;
        acc2[9].x  += s2.y * xv.x; acc2[9].y  += s2.y * xv.y; acc2[9].z  += s2.y * xv.z; acc2[9].w  += s2.y * xv.w;
        acc2[10].x += s2.z * xv.x; acc2[10].y += s2.z * xv.y; acc2[10].z += s2.z * xv.z; acc2[10].w += s2.z * xv.w;
        acc2[11].x += s2.w * xv.x; acc2[11].y += s2.w * xv.y; acc2[11].z += s2.w * xv.z; acc2[11].w += s2.w * xv.w;
        acc2[12].x += s3.x * xv.x; acc2[12].y += s3.x * xv.y; acc2[12].z += s3.x * xv.z; acc2[12].w += s3.x * xv.w;
        acc2[13].x += s3.y * xv.x; acc2[13].y += s3.y * xv.y; acc2[13].z += s3.y * xv.z; acc2[13].w += s3.y * xv.w;
        acc2[14].x += s3.z * xv.x; acc2[14].y += s3.z * xv.y; acc2[14].z += s3.z * xv.z; acc2[14].w += s3.z * xv.w;
        acc2[15].x += s3.w * xv.x; acc2[15].y += s3.w * xv.y; acc2[15].z += s3.w * xv.z; acc2[15].w += s3.w * xv.w;
    }
    float* op = spart + ((size_t)blockIdx.x * 16) * 1024 + tid * 4;
#pragma unroll
    for (int j = 0; j < 16; ++j)
        *(float4*)(op + (size_t)j * 1024) = acc2[j];
}

// ---------------------------------------------------------------------------
// K1b: per-token entmax15 epilogue -> combine only.
// ---------------------------------------------------------------------------
__global__ __launch_bounds__(64) void k_epi(
    const float* __restrict__ lgbuf, const float* __restrict__ cj,
    const float* __restrict__ wbuf, const float* __restrict__ s1p,
    float* __restrict__ combine)
{
    int tok = blockIdx.x * 64 + threadIdx.x;
    const float* lp = lgbuf + (size_t)tok * 20;
    float s[17];
    float4 q0 = *(const float4*)(lp + 0);
    float4 q1 = *(const float4*)(lp + 4);
    float4 q2 = *(const float4*)(lp + 8);
    float4 q3 = *(const float4*)(lp + 12);
    s[0] = q0.x; s[1] = q0.y; s[2] = q0.z; s[3] = q0.w;
    s[4] = q1.x; s[5] = q1.y; s[6] = q1.z; s[7] = q1.w;
    s[8] = q2.x; s[9] = q2.y; s[10] = q2.z; s[11] = q2.w;
    s[12] = q3.x; s[13] = q3.y; s[14] = q3.z; s[15] = q3.w;
    s[16] = lp[16];

    float ss = s[16] + wbuf[2048];
    float rn = 1.0f / (sqrtf(ss) + 1e-6f);
    float inv1h = 0.5f / s1p[0];
    float lg[16];
#pragma unroll
    for (int j = 0; j < 16; ++j) lg[j] = (s[j] + cj[j]) * rn;

    float z[16], zmax = -1e30f;
#pragma unroll
    for (int j = 0; j < 16; ++j) { z[j] = lg[j] * inv1h; zmax = fmaxf(zmax, z[j]); }
#pragma unroll
    for (int j = 0; j < 16; ++j) z[j] -= zmax;
    float zsr[16];
#pragma unroll
    for (int j = 0; j < 16; ++j) zsr[j] = z[j];
#pragma unroll
    for (int rr = 0; rr < 16; ++rr) {
#pragma unroll
        for (int jj = (rr & 1); jj + 1 < 16; jj += 2) {
            float aa = zsr[jj], bb = zsr[jj + 1];
            zsr[jj] = fmaxf(aa, bb);
            zsr[jj + 1] = fminf(aa, bb);
        }
    }
    float cs = 0.f, css = 0.f, tau_star = 0.f;
#pragma unroll
    for (int kk = 1; kk <= 16; ++kk) {
        cs += zsr[kk - 1];
        css += zsr[kk - 1] * zsr[kk - 1];
        float fk = (float)kk;
        float mean = cs / fk, msq = css / fk;
        float ssv = fk * (msq - mean * mean);
        float delta = fmaxf((1.0f - ssv) / fk, 1e-12f);
        float tau = mean - sqrtf(delta);
        tau_star = (tau <= zsr[kk - 1]) ? tau : tau_star;
    }
    float4* cw = (float4*)(combine + (size_t)tok * 16);
#pragma unroll
    for (int q4i = 0; q4i < 4; ++q4i) {
        float4 cv;
        float t0 = fmaxf(z[q4i * 4 + 0] - tau_star, 0.f);
        float t1 = fmaxf(z[q4i * 4 + 1] - tau_star, 0.f);
        float t2 = fmaxf(z[q4i * 4 + 2] - tau_star, 0.f);
        float t3 = fmaxf(z[q4i * 4 + 3] - tau_star, 0.f);
        cv.x = t0 * t0; cv.y = t1 * t1; cv.z = t2 * t2; cv.w = t3 * t3;
        cw[q4i] = cv;
    }
}

// ---------------------------------------------------------------------------
// K2c: coalesced reduce over 64 nc chunks. slotsT[e][k][t] (t=b*2+s, j=e*2+s).
// ---------------------------------------------------------------------------
__global__ __launch_bounds__(256) void k_slots_reduce(
    const float* __restrict__ spart, float* __restrict__ slotsT)
{
    int j = blockIdx.x, b = blockIdx.y;
    int tid = threadIdx.x;
    const float* p = spart + ((size_t)(b * 64) * 16 + j) * 1024 + tid * 4;
    float4 s; s.x = 0.f; s.y = 0.f; s.z = 0.f; s.w = 0.f;
#pragma unroll 8
    for (int nc = 0; nc < 64; ++nc) {
        float4 v = *(const float4*)(p + (size_t)nc * 16384);
        s.x += v.x; s.y += v.y; s.z += v.z; s.w += v.w;
    }
    int e = j >> 1, sl = j & 1;
    int t = b * 2 + sl;
    float* o = slotsT + ((size_t)e * 1024 + tid * 4) * 16 + t;
    o[0] = s.x; o[16] = s.y; o[32] = s.z; o[48] = s.w;
}

// ---------------------------------------------------------------------------
// D1: split-K h-partials. p1[ks=16][e][col=4096][t=16], K-chunk 64.
// ---------------------------------------------------------------------------
__global__ __launch_bounds__(256) void k_mlp1(
    const float* __restrict__ w1, const float* __restrict__ slotsT,
    float* __restrict__ p1)
{
    __shared__ float sm[1024];
    int cc = blockIdx.x, ks = blockIdx.y, e = blockIdx.z;
    int tid = threadIdx.x;
    int k0 = ks * 64;
    int col = cc * 1024 + tid * 4;
    ((float4*)sm)[tid] = ((const float4*)(slotsT + ((size_t)e * 1024 + k0) * 16))[tid];
    __syncthreads();

    const float* wp = w1 + (size_t)e * 1024 * 4096 + (size_t)k0 * 4096 + col;
    float4 acc[16];
#pragma unroll
    for (int t = 0; t < 16; ++t) { acc[t].x = 0.f; acc[t].y = 0.f; acc[t].z = 0.f; acc[t].w = 0.f; }
#pragma unroll 8
    for (int kk = 0; kk < 64; ++kk) {
        float4 w = *(const float4*)(wp + (size_t)kk * 4096);
        const float4* q4 = (const float4*)(sm + kk * 16);
        float4 s0 = q4[0], s1 = q4[1], s2 = q4[2], s3 = q4[3];
        acc[0].x  += s0.x * w.x; acc[0].y  += s0.x * w.y; acc[0].z  += s0.x * w.z; acc[0].w  += s0.x * w.w;
        acc[1].x  += s0.y * w.x; acc[1].y  += s0.y * w.y; acc[1].z  += s0.y * w.z; acc[1].w  += s0.y * w.w;
        acc[2].x  += s0.z * w.x; acc[2].y  += s0.z * w.y; acc[2].z  += s0.z * w.z; acc[2].w  += s0.z * w.w;
        acc[3].x  += s0.w * w.x; acc[3].y  += s0.w * w.y; acc[3].z  += s0.w * w.z; acc[3].w  += s0.w * w.w;
        acc[4].x  += s1.x * w.x; acc[4].y  += s1.x * w.y; acc[4].z  += s1.x * w.z; acc[4].w  += s1.x * w.w;
        acc[5].x  += s1.y * w.x; acc[5].y  += s1.y * w.y; acc[5].z  += s1.y * w.z; acc[5].w  += s1.y * w.w;
        acc[6].x  += s1.z * w.x; acc[6].y  += s1.z * w.y; acc[6].z  += s1.z * w.z; acc[6].w  += s1.z * w.w;
        acc[7].x  += s1.w * w.x; acc[7].y  += s1.w * w.y; acc[7].z  += s1.w * w.z; acc[7].w  += s1.w * w.w;
        acc[8].x  += s2.x * w.x; acc[8].y  += s2.x * w.y; acc[8].z  += s2.x * w.z; acc[8].w  += s2.x * w.w;
        acc[9].x  += s2.y * w.x; acc[9].y  += s2.y * w.y; acc[9].z  += s2.y * w.z; acc[9].w  += s2.y * w.w;
        acc[10].x += s2.z * w.x; acc[10].y += s2.z * w.y; acc[10].z += s2.z * w.z; acc[10].w += s2.z * w.w;
        acc[11].x += s2.w * w.x; acc[11].y += s2.w * w.y; acc[11].z += s2.w * w.z; acc[11].w += s2.w * w.w;
        acc[12].x += s3.x * w.x; acc[12].y += s3.x * w.y; acc[12].z += s3.x * w.z; acc[12].w += s3.x * w.w;
        acc[13].x += s3.y * w.x; acc[13].y += s3.y * w.y; acc[13].z += s3.y * w.z; acc[13].w += s3.y * w.w;
        acc[14].x += s3.z * w.x; acc[14].y += s3.z * w.y; acc[14].z += s3.z * w.z; acc[14].w += s3.z * w.w;
        acc[15].x += s3.w * w.x; acc[15].y += s3.w * w.y; acc[15].z += s3.w * w.z; acc[15].w += s3.w * w.w;
    }
    float av0[16], av1[16], av2[16], av3[16];
#pragma unroll
    for (int t = 0; t < 16; ++t) { av0[t] = acc[t].x; av1[t] = acc[t].y; av2[t] = acc[t].z; av3[t] = acc[t].w; }
    float* op = p1 + (((size_t)ks * 8 + e) * 4096 + col) * 16;
#pragma unroll
    for (int q = 0; q < 4; ++q) {
        *(float4*)(op + 0 * 16 + q * 4) = make_float4(av0[q*4+0], av0[q*4+1], av0[q*4+2], av0[q*4+3]);
        *(float4*)(op + 1 * 16 + q * 4) = make_float4(av1[q*4+0], av1[q*4+1], av1[q*4+2], av1[q*4+3]);
        *(float4*)(op + 2 * 16 + q * 4) = make_float4(av2[q*4+0], av2[q*4+1], av2[q*4+2], av2[q*4+3]);
        *(float4*)(op + 3 * 16 + q * 4) = make_float4(av3[q*4+0], av3[q*4+1], av3[q*4+2], av3[q*4+3]);
    }
}

// ---------------------------------------------------------------------------
// D2: fused {reduce p1 (16 chunks) + bias + gelu} -> LDS, then out-partials.
// p2[ks=64][e][col=1024][t=16], hidden-chunk 64. grid (64, 8) = 512 blocks.
// ---------------------------------------------------------------------------
__global__ __launch_bounds__(256) void k_mlp2f(
    const float* __restrict__ w2, const float* __restrict__ p1,
    const float* __restrict__ b1, float* __restrict__ p2)
{
    __shared__ float sm[1024];
    int ks = blockIdx.x, e = blockIdx.y;
    int tid = threadIdx.x;
    int k0 = ks * 64;                  // hidden-col chunk [k0, k0+64)
    int col = tid * 4;

    {
        int fidx = tid;
        const float* pp = p1 + (size_t)e * 65536 + (size_t)k0 * 16 + fidx * 4;
        float4 s; s.x = 0.f; s.y = 0.f; s.z = 0.f; s.w = 0.f;
#pragma unroll
        for (int ksp = 0; ksp < 16; ++ksp) {
            float4 v = *(const float4*)(pp + (size_t)ksp * 524288);
            s.x += v.x; s.y += v.y; s.z += v.z; s.w += v.w;
        }
        int colh = k0 + (fidx >> 2);
        float bb = b1[(size_t)e * 4096 + colh];
        s.x += bb; s.y += bb; s.z += bb; s.w += bb;
        s.x = 0.5f * s.x * (1.0f + erff(s.x * 0.70710678118654752f));
        s.y = 0.5f * s.y * (1.0f + erff(s.y * 0.70710678118654752f));
        s.z = 0.5f * s.z * (1.0f + erff(s.z * 0.70710678118654752f));
        s.w = 0.5f * s.w * (1.0f + erff(s.w * 0.70710678118654752f));
        *(float4*)(&sm[fidx * 4]) = s;
    }
    __syncthreads();

    const float* wp = w2 + (size_t)e * 4096 * 1024 + (size_t)k0 * 1024 + col;
    float4 acc[16];
#pragma unroll
    for (int t = 0; t < 16; ++t) { acc[t].x = 0.f; acc[t].y = 0.f; acc[t].z = 0.f; acc[t].w = 0.f; }
#pragma unroll 8
    for (int kk = 0; kk < 64; ++kk) {
        float4 w = *(const float4*)(wp + (size_t)kk * 1024);
        const float4* q4 = (const float4*)(sm + kk * 16);
        float4 s0 = q4[0], s1 = q4[1], s2 = q4[2], s3 = q4[3];
        acc[0].x  += s0.x * w.x; acc[0].y  += s0.x * w.y; acc[0].z  += s0.x * w.z; acc[0].w  += s0.x * w.w;
        acc[1].x  += s0.y * w.x; acc[1].y  += s0.y * w.y; acc[1].z  += s0.y * w.z; acc[1].w  += s0.y * w.w;
        acc[2].x  += s0.z * w.x; acc[2].y  += s0.z * w.y; acc[2].z  += s0.z * w.z; acc[2].w  += s0.z * w.w;
        acc[3].x  += s0.w * w.x; acc[3].y  += s0.w * w.y; acc[3].z  += s0.w * w.z; acc[3].w  += s0.w * w.w;
        acc[4].x  += s1.x * w.x; acc[4].y  += s1.x * w.y; acc[4].z  += s1.x * w.z; acc[4].w  += s1.x * w.w;
        acc[5].x  += s1.y * w.x; acc[5].y  += s1.y * w.y; acc[5].z  += s1.y * w.z; acc[5].w  += s1.y * w.w;
        acc[6].x  += s1.z * w.x; acc[6].y  += s1.z * w.y; acc[6].z  += s1.z * w.z; acc[6].w  += s1.z * w.w;
        acc[7].x  += s1.w * w.x; acc[7].y  += s1.w * w.y; acc[7].z  += s1.w * w.z; acc[7].w  += s1.w * w.w;
        acc[8].x  += s2.x * w.x; acc[8].y  += s2.x * w.y; acc[8].z  += s2.x * w.z; acc[8].w  += s2.x * w.w;
        acc[9].x  += s2.y * w.x; acc[9].y  += s2.y * w.y; acc[9].z  += s2.y * w.z; acc[9].w  += s2.y * w.w;
        acc[10].x += s2.z * w.x; acc[10].y += s2.z * w.y; acc[10].z += s2.z * w.z; acc[10].w += s2.z * w.w;
        acc[11].x += s2.w * w.x; acc[11].y += s2.w * w.y; acc[11].z += s2.w * w.z; acc[11].w += s2.w * w.w;
        acc[12].x += s3.x * w.x; acc[12].y += s3.x * w.y; acc[12].z += s3.x * w.z; acc[12].w += s3.x * w.w;
        acc[13].x += s3.y * w.x; acc[13].y += s3.y * w.y; acc[13].z += s3.y * w.z; acc[13].w += s3.y * w.w;
        acc[14].x += s3.z * w.x; acc[14].y += s3.z * w.y; acc[14].z += s3.z * w.z; acc[14].w += s3.z * w.w;
        acc[15].x += s3.w * w.x; acc[15].y += s3.w * w.y; acc[15].z += s3.w * w.z; acc[15].w += s3.w * w.w;
    }
    float av0[16], av1[16], av2[16], av3[16];
#pragma unroll
    for (int t = 0; t < 16; ++t) { av0[t] = acc[t].x; av1[t] = acc[t].y; av2[t] = acc[t].z; av3[t] = acc[t].w; }
    float* op = p2 + (((size_t)ks * 8 + e) * 1024 + col) * 16;
#pragma unroll
    for (int q = 0; q < 4; ++q) {
        *(float4*)(op + 0 * 16 + q * 4) = make_float4(av0[q*4+0], av0[q*4+1], av0[q*4+2], av0[q*4+3]);
        *(float4*)(op + 1 * 16 + q * 4) = make_float4(av1[q*4+0], av1[q*4+1], av1[q*4+2], av1[q*4+3]);
        *(float4*)(op + 2 * 16 + q * 4) = make_float4(av2[q*4+0], av2[q*4+1], av2[q*4+2], av2[q*4+3]);
        *(float4*)(op + 3 * 16 + q * 4) = make_float4(av3[q*4+0], av3[q*4+1], av3[q*4+2], av3[q*4+3]);
    }
}

// ---------------------------------------------------------------------------
// D2r: co[b][j][d] = Σ_ks p2 + b2 (64 ks chunks). 8192 elems x 4/thread.
// ---------------------------------------------------------------------------
__global__ __launch_bounds__(256) void k_red2(
    const float* __restrict__ p2, const float* __restrict__ b2,
    float* __restrict__ co)
{
    int idx = blockIdx.x * 256 + threadIdx.x;    // 0..32767
    int q = idx & 3, d = (idx >> 2) & 1023, e = idx >> 12;
    const float* p = p2 + ((size_t)e * 1024 + d) * 16 + q * 4;
    float4 s; s.x = 0.f; s.y = 0.f; s.z = 0.f; s.w = 0.f;
#pragma unroll 8
    for (int ks = 0; ks < 64; ++ks) {
        float4 v = *(const float4*)(p + (size_t)ks * 131072);
        s.x += v.x; s.y += v.y; s.z += v.z; s.w += v.w;
    }
    float bb = b2[(size_t)e * 1024 + d];
    float vv[4] = { s.x + bb, s.y + bb, s.z + bb, s.w + bb };
#pragma unroll
    for (int u = 0; u < 4; ++u) {
        int t = q * 4 + u;
        int b = t >> 1, sl = t & 1;
        co[((size_t)b * 16 + e * 2 + sl) * 1024 + d] = vv[u];
    }
}

// ---------------------------------------------------------------------------
// KE: out[b,n,:] = sum_j combine[b,n,j] * co[b][j][:]. Combine tile in LDS.
// ---------------------------------------------------------------------------
__global__ __launch_bounds__(256) void k_out(
    const float* __restrict__ co, const float* __restrict__ combine,
    float* __restrict__ out)
{
    __shared__ float sm[1024];
    int b = blockIdx.y, tile = blockIdx.x;     // 64 tokens per tile
    int tid = threadIdx.x;
    ((float4*)sm)[tid] = ((const float4*)(combine + ((size_t)b * N_ + tile * 64) * 16))[tid];
    float4 cv[16];
#pragma unroll
    for (int j = 0; j < 16; ++j)
        cv[j] = ((const float4*)(co + ((size_t)b * 16 + j) * 1024))[tid];
    __syncthreads();
    float4* ob = (float4*)(out + ((size_t)b * N_ + tile * 64) * 1024) + tid;
#pragma unroll 2
    for (int it = 0; it < 64; ++it) {
        const float* cm = sm + it * 16;
        float4 acc; acc.x = 0.f; acc.y = 0.f; acc.z = 0.f; acc.w = 0.f;
#pragma unroll
        for (int j = 0; j < 16; ++j) {
            float wj = cm[j];
            acc.x += wj * cv[j].x; acc.y += wj * cv[j].y;
            acc.z += wj * cv[j].z; acc.w += wj * cv[j].w;
        }
        ob[(size_t)it * 256] = acc;
    }
}

// ---------------------------------------------------------------------------
extern "C" void kernel_launch(void* const* d_in, const int* in_sizes, int n_in,
                              void* d_out, int out_size, void* d_ws, size_t ws_size,
                              hipStream_t stream)
{
    const float* x   = (const float*)d_in[0];
    const float* phi = (const float*)d_in[2];
    const float* kg  = (const float*)d_in[3];
    const float* kb  = (const float*)d_in[4];
    const float* qg  = (const float*)d_in[5];
    const float* qb  = (const float*)d_in[6];
    const float* lng = (const float*)d_in[7];
    const float* lnb = (const float*)d_in[8];
    const float* s0  = (const float*)d_in[9];
    const float* s1  = (const float*)d_in[10];
    const float* w1  = (const float*)d_in[11];
    const float* b1  = (const float*)d_in[12];
    const float* w2  = (const float*)d_in[13];
    const float* b2  = (const float*)d_in[14];
    // occ weights d_in[15..18]: provably dead (exact-zero combine/dispatch)

    float* out = (float*)d_out;
    float* ws  = (float*)d_ws;

    float* qk       = ws;                        // 16384
    float* cj       = qk + 16384;                // 16
    float* wbuf     = cj + 16;                   // 2064
    float* combine  = wbuf + 2064;               // 524288
    float* slotsT   = combine + 524288;          // 131072
    float* co       = slotsT + 131072;           // 131072
    float* lgbuf    = co + 131072;               // 655360 (lives with spart)
    float* arenaA   = lgbuf + 655360;            // 8388608 (spart -> p1)
    float* arenaB   = arenaA + 8388608;          // 8388608 (p2)
    float* spart    = arenaA;
    float* p1       = arenaA;
    float* p2       = arenaB;

    k_prep        <<<dim3(17),        dim3(64),  0, stream>>>(phi, qg, qb, lng, lnb, kg, kb, qk, cj, wbuf);
    k_fused       <<<dim3(512),       dim3(256), 0, stream>>>(x, qk, wbuf, cj, s0, lgbuf, spart);
    k_epi         <<<dim3(512),       dim3(64),  0, stream>>>(lgbuf, cj, wbuf, s1, combine);
    k_slots_reduce<<<dim3(16, 8),     dim3(256), 0, stream>>>(spart, slotsT);
    k_mlp1        <<<dim3(4, 16, 8),  dim3(256), 0, stream>>>(w1, slotsT, p1);
    k_mlp2f       <<<dim3(64, 8),     dim3(256), 0, stream>>>(w2, p1, b1, p2);
    k_red2        <<<dim3(128),       dim3(256), 0, stream>>>(p2, b2, co);
    k_out         <<<dim3(64, 8),     dim3(256), 0, stream>>>(co, combine, out);
}

// Round 17
// 214.073 us; speedup vs baseline: 1.2185x; 1.2185x over previous
//
#include <hip/hip_runtime.h>
#include <hip/hip_bf16.h>

#define B_ 8
#define N_ 4096
#define D_ 1024

#define AS1 __attribute__((address_space(1)))
#define AS3 __attribute__((address_space(3)))
__device__ __forceinline__ void gld16(const float* g, float* l) {
    __builtin_amdgcn_global_load_lds((const AS1 void*)g, (AS3 void*)l, 16, 0, 0);
}

// ---------------------------------------------------------------------------
// K0: prep. blocks 0..15: qk[r] = (l2norm(layernorm(phi[r]*qg+qb))) ⊙ kg,
//                         cj[r] = Σ q·kb.   block 16: w2=kg², w1=2kg·kb, C=Σkb².
// ---------------------------------------------------------------------------
__global__ __launch_bounds__(64) void k_prep(
    const float* __restrict__ phi, const float* __restrict__ qg, const float* __restrict__ qb,
    const float* __restrict__ lng, const float* __restrict__ lnb,
    const float* __restrict__ kg, const float* __restrict__ kb,
    float* __restrict__ qk, float* __restrict__ cj, float* __restrict__ wbuf)
{
    int r = blockIdx.x;        // 0..16
    int lane = threadIdx.x;    // 0..63
    if (r == 16) {
        float cacc = 0.f;
#pragma unroll
        for (int c = 0; c < 16; ++c) {
            int i = c * 64 + lane;
            float g = kg[i], b = kb[i];
            wbuf[i] = g * g;
            wbuf[1024 + i] = 2.0f * g * b;
            cacc += b * b;
        }
#pragma unroll
        for (int m = 32; m; m >>= 1) cacc += __shfl_xor(cacc, m);
        if (lane == 0) wbuf[2048] = cacc;
        return;
    }
    const float* pr = phi + (size_t)r * D_;
    float v[16];
    float s1 = 0.f;
#pragma unroll
    for (int c = 0; c < 16; ++c) {
        int i = c * 64 + lane;
        v[c] = pr[i] * qg[i] + qb[i];
        s1 += v[c];
    }
#pragma unroll
    for (int m = 32; m; m >>= 1) s1 += __shfl_xor(s1, m);
    float mu = s1 * (1.0f / D_);
    float s2 = 0.f;
#pragma unroll
    for (int c = 0; c < 16; ++c) { float dd = v[c] - mu; s2 += dd * dd; }
#pragma unroll
    for (int m = 32; m; m >>= 1) s2 += __shfl_xor(s2, m);
    float var = s2 * (1.0f / D_);
    float inv = 1.0f / sqrtf(var + 1e-5f);
    float u[16];
    float s3 = 0.f;
#pragma unroll
    for (int c = 0; c < 16; ++c) {
        int i = c * 64 + lane;
        u[c] = (v[c] - mu) * inv * lng[i] + lnb[i];
        s3 += u[c] * u[c];
    }
#pragma unroll
    for (int m = 32; m; m >>= 1) s3 += __shfl_xor(s3, m);
    float rn = 1.0f / (sqrtf(s3) + 1e-6f);
    float cacc = 0.f;
#pragma unroll
    for (int c = 0; c < 16; ++c) {
        int i = c * 64 + lane;
        float qv = u[c] * rn;
        qk[(size_t)r * D_ + i] = qv * kg[i];
        cacc += qv * kb[i];
    }
#pragma unroll
    for (int m = 32; m; m >>= 1) cacc += __shfl_xor(cacc, m);
    if (lane == 0) cj[r] = cacc;
}

// ---------------------------------------------------------------------------
// K1: FUSED logits + softmax-dispatch + slot-partials.  (round-13 optimum)
// 512 threads/block, 64 tokens/block, 2 tokens/thread, 512 blocks.
// LDS = exactly 64 KB (qk only -> 2 blocks/CU, 16 waves/CU, VGPR 64, no
// spill). w2|w1 from global (L2 broadcast). Barrier-free d-loop. Phase 2
// splits by J-HALF: thread-half th owns experts th*8..th*8+7 (acc2[8]).
// ---------------------------------------------------------------------------
__global__ __launch_bounds__(512) void k_fused(
    const float* __restrict__ x, const float* __restrict__ qk,
    const float* __restrict__ wbuf, const float* __restrict__ cj,
    const float* __restrict__ s0p,
    float* __restrict__ lgbuf, float* __restrict__ spart)
{
    __shared__ float smem[16384];  // 64 KB: qs[16][1024]; later red|sums|disp
    float* qs   = smem;
    float* red  = smem;            // 8704 floats
    float* sums = smem + 8704;     // 1088
    float* disp = smem + 9792;     // 1024

    int tid = threadIdx.x;
    int tok0 = blockIdx.x * 64;
    int wid = tid >> 6;            // 0..7
    int r0 = tid >> 4;             // 0..31  (token within half)
    int c4 = (tid & 15) * 4;       // c-slice within 64-float chunk

    // ---- one-time stage: qk (8 gld16/thread, linear both sides)
#pragma unroll
    for (int i = 0; i < 8; ++i)
        gld16(qk + (size_t)(i * 512 + tid) * 4, &qs[(i * 512 + wid * 64) * 4]);
    __syncthreads();

    float acc[2][17];
#pragma unroll
    for (int u = 0; u < 2; ++u)
#pragma unroll
        for (int v = 0; v < 17; ++v) acc[u][v] = 0.f;

    // ---- barrier-free d-loop: thread owns tokens {r0, 32+r0}, c-slice c4
#pragma unroll 2
    for (int dc = 0; dc < 16; ++dc) {
        float4 xv0 = *(const float4*)(x + (size_t)(tok0 + r0) * D_ + dc * 64 + c4);
        float4 xv1 = *(const float4*)(x + (size_t)(tok0 + 32 + r0) * D_ + dc * 64 + c4);
        float4 w2v = *(const float4*)(wbuf + dc * 64 + c4);          // L2 broadcast
        float4 w1v = *(const float4*)(wbuf + 1024 + dc * 64 + c4);
        acc[0][16] += (w2v.x * xv0.x + w1v.x) * xv0.x + (w2v.y * xv0.y + w1v.y) * xv0.y
                    + (w2v.z * xv0.z + w1v.z) * xv0.z + (w2v.w * xv0.w + w1v.w) * xv0.w;
        acc[1][16] += (w2v.x * xv1.x + w1v.x) * xv1.x + (w2v.y * xv1.y + w1v.y) * xv1.y
                    + (w2v.z * xv1.z + w1v.z) * xv1.z + (w2v.w * xv1.w + w1v.w) * xv1.w;
        const float* qb = qs + dc * 64 + c4;
#pragma unroll
        for (int j = 0; j < 16; ++j) {
            float4 q4 = *(const float4*)(qb + j * 1024);
            acc[0][j] += xv0.x * q4.x + xv0.y * q4.y + xv0.z * q4.z + xv0.w * q4.w;
            acc[1][j] += xv1.x * q4.x + xv1.y * q4.y + xv1.z * q4.z + xv1.w * q4.w;
        }
    }
    __syncthreads();   // all qs reads done before reuse as red

    // ---- c-reduce: 2 half-passes of 32 tokens (static acc index)
#pragma unroll
    for (int half = 0; half < 2; ++half) {
#pragma unroll
        for (int v = 0; v < 17; ++v)
            red[(r0 * 17 + v) * 16 + (tid & 15)] = acc[half][v];
        __syncthreads();
#pragma unroll
        for (int it = 0; it < 2; ++it) {
            int idx = tid + it * 512;
            if (idx < 544) {
                const float4* p = (const float4*)(red + idx * 16);
                float4 a = p[0], b = p[1], cq = p[2], dq = p[3];
                float sum = (((a.x + a.y) + (a.z + a.w)) + ((b.x + b.y) + (b.z + b.w)))
                          + (((cq.x + cq.y) + (cq.z + cq.w)) + ((dq.x + dq.y) + (dq.z + dq.w)));
                int t = idx / 17, v = idx - t * 17;
                lgbuf[(size_t)(tok0 + half * 32 + t) * 20 + v] = sum;
                sums[(half * 32 + t) * 17 + v] = sum;
            }
        }
        __syncthreads();
    }

    // ---- softmax-dispatch (entmax in k_epi): one thread per token
    if (tid < 64) {
        const float* sp = sums + tid * 17;
        float ss = sp[16] + wbuf[2048];
        float rn = 1.0f / (sqrtf(ss) + 1e-6f);
        float inv0 = 1.0f / s0p[0];
        float lg[16];
#pragma unroll
        for (int j = 0; j < 16; ++j) lg[j] = (sp[j] + cj[j]) * rn;
        float dsp[16];
#pragma unroll
        for (int sl = 0; sl < 2; ++sl) {
            float a[8], m = -1e30f;
#pragma unroll
            for (int ee = 0; ee < 8; ++ee) { a[ee] = lg[2 * ee + sl] * inv0; m = fmaxf(m, a[ee]); }
            float den = 0.f;
#pragma unroll
            for (int ee = 0; ee < 8; ++ee) { a[ee] = expf(a[ee] - m); den += a[ee]; }
            float r = 1.0f / den;
#pragma unroll
            for (int ee = 0; ee < 8; ++ee) dsp[2 * ee + sl] = a[ee] * r;
        }
#pragma unroll
        for (int q4i = 0; q4i < 4; ++q4i)
            *(float4*)(&disp[tid * 16 + q4i * 4]) =
                make_float4(dsp[q4i * 4 + 0], dsp[q4i * 4 + 1], dsp[q4i * 4 + 2], dsp[q4i * 4 + 3]);
    }
    __syncthreads();

    // ---- phase 2: slot partials, J-HALF per thread-half (x L2-warm)
    int th = tid >> 8;             // 0/1: experts [th*8, th*8+8)
    int cix = tid & 255;           // float4 column of d
    const float* xp = x + (size_t)tok0 * D_ + cix * 4;
    float4 acc2[8];
#pragma unroll
    for (int j = 0; j < 8; ++j) { acc2[j].x = 0.f; acc2[j].y = 0.f; acc2[j].z = 0.f; acc2[j].w = 0.f; }
#pragma unroll 8
    for (int n = 0; n < 64; ++n) {
        float4 xv = *(const float4*)(xp + (size_t)n * D_);
        const float4* q4 = (const float4*)(disp + n * 16 + th * 8);
        float4 s0 = q4[0], s1 = q4[1];
        acc2[0].x += s0.x * xv.x; acc2[0].y += s0.x * xv.y; acc2[0].z += s0.x * xv.z; acc2[0].w += s0.x * xv.w;
        acc2[1].x += s0.y * xv.x; acc2[1].y += s0.y * xv.y; acc2[1].z += s0.y * xv.z; acc2[1].w += s0.y * xv.w;
        acc2[2].x += s0.z * xv.x; acc2[2].y += s0.z * xv.y; acc2[2].z += s0.z * xv.z; acc2[2].w += s0.z * xv.w;
        acc2[3].x += s0.w * xv.x; acc2[3].y += s0.w * xv.y; acc2[3].z += s0.w * xv.z; acc2[3].w += s0.w * xv.w;
        acc2[4].x += s1.x * xv.x; acc2[4].y += s1.x * xv.y; acc2[4].z += s1.x * xv.z; acc2[4].w += s1.x * xv.w;
        acc2[5].x += s1.y * xv.x; acc2[5].y += s1.y * xv.y; acc2[5].z += s1.y * xv.z; acc2[5].w += s1.y * xv.w;
        acc2[6].x += s1.z * xv.x; acc2[6].y += s1.z * xv.y; acc2[6].z += s1.z * xv.z; acc2[6].w += s1.z * xv.w;
        acc2[7].x += s1.w * xv.x; acc2[7].y += s1.w * xv.y; acc2[7].z += s1.w * xv.z; acc2[7].w += s1.w * xv.w;
    }
    float* op = spart + ((size_t)blockIdx.x * 16 + th * 8) * 1024 + cix * 4;
#pragma unroll
    for (int j = 0; j < 8; ++j)
        *(float4*)(op + (size_t)j * 1024) = acc2[j];
}

// ---------------------------------------------------------------------------
// K1b: per-token entmax15 epilogue -> combine only.
// ---------------------------------------------------------------------------
__global__ __launch_bounds__(64) void k_epi(
    const float* __restrict__ lgbuf, const float* __restrict__ cj,
    const float* __restrict__ wbuf, const float* __restrict__ s1p,
    float* __restrict__ combine)
{
    int tok = blockIdx.x * 64 + threadIdx.x;
    const float* lp = lgbuf + (size_t)tok * 20;
    float s[17];
    float4 q0 = *(const float4*)(lp + 0);
    float4 q1 = *(const float4*)(lp + 4);
    float4 q2 = *(const float4*)(lp + 8);
    float4 q3 = *(const float4*)(lp + 12);
    s[0] = q0.x; s[1] = q0.y; s[2] = q0.z; s[3] = q0.w;
    s[4] = q1.x; s[5] = q1.y; s[6] = q1.z; s[7] = q1.w;
    s[8] = q2.x; s[9] = q2.y; s[10] = q2.z; s[11] = q2.w;
    s[12] = q3.x; s[13] = q3.y; s[14] = q3.z; s[15] = q3.w;
    s[16] = lp[16];

    float ss = s[16] + wbuf[2048];
    float rn = 1.0f / (sqrtf(ss) + 1e-6f);
    float inv1h = 0.5f / s1p[0];
    float lg[16];
#pragma unroll
    for (int j = 0; j < 16; ++j) lg[j] = (s[j] + cj[j]) * rn;

    float z[16], zmax = -1e30f;
#pragma unroll
    for (int j = 0; j < 16; ++j) { z[j] = lg[j] * inv1h; zmax = fmaxf(zmax, z[j]); }
#pragma unroll
    for (int j = 0; j < 16; ++j) z[j] -= zmax;
    float zsr[16];
#pragma unroll
    for (int j = 0; j < 16; ++j) zsr[j] = z[j];
#pragma unroll
    for (int rr = 0; rr < 16; ++rr) {
#pragma unroll
        for (int jj = (rr & 1); jj + 1 < 16; jj += 2) {
            float aa = zsr[jj], bb = zsr[jj + 1];
            zsr[jj] = fmaxf(aa, bb);
            zsr[jj + 1] = fminf(aa, bb);
        }
    }
    float cs = 0.f, css = 0.f, tau_star = 0.f;
#pragma unroll
    for (int kk = 1; kk <= 16; ++kk) {
        cs += zsr[kk - 1];
        css += zsr[kk - 1] * zsr[kk - 1];
        float fk = (float)kk;
        float mean = cs / fk, msq = css / fk;
        float ssv = fk * (msq - mean * mean);
        float delta = fmaxf((1.0f - ssv) / fk, 1e-12f);
        float tau = mean - sqrtf(delta);
        tau_star = (tau <= zsr[kk - 1]) ? tau : tau_star;
    }
    float4* cw = (float4*)(combine + (size_t)tok * 16);
#pragma unroll
    for (int q4i = 0; q4i < 4; ++q4i) {
        float4 cv;
        float t0 = fmaxf(z[q4i * 4 + 0] - tau_star, 0.f);
        float t1 = fmaxf(z[q4i * 4 + 1] - tau_star, 0.f);
        float t2 = fmaxf(z[q4i * 4 + 2] - tau_star, 0.f);
        float t3 = fmaxf(z[q4i * 4 + 3] - tau_star, 0.f);
        cv.x = t0 * t0; cv.y = t1 * t1; cv.z = t2 * t2; cv.w = t3 * t3;
        cw[q4i] = cv;
    }
}

// ---------------------------------------------------------------------------
// K2c: coalesced reduce over 64 nc chunks. slotsT[e][k][t] (t=b*2+s, j=e*2+s).
// ---------------------------------------------------------------------------
__global__ __launch_bounds__(256) void k_slots_reduce(
    const float* __restrict__ spart, float* __restrict__ slotsT)
{
    int j = blockIdx.x, b = blockIdx.y;
    int tid = threadIdx.x;
    const float* p = spart + ((size_t)(b * 64) * 16 + j) * 1024 + tid * 4;
    float4 s; s.x = 0.f; s.y = 0.f; s.z = 0.f; s.w = 0.f;
#pragma unroll 8
    for (int nc = 0; nc < 64; ++nc) {
        float4 v = *(const float4*)(p + (size_t)nc * 16384);
        s.x += v.x; s.y += v.y; s.z += v.z; s.w += v.w;
    }
    int e = j >> 1, sl = j & 1;
    int t = b * 2 + sl;
    float* o = slotsT + ((size_t)e * 1024 + tid * 4) * 16 + t;
    o[0] = s.x; o[16] = s.y; o[32] = s.z; o[48] = s.w;
}

// ---------------------------------------------------------------------------
// D1: split-K h-partials. p1[ks=16][e][col=4096][t=16], K-chunk 64.
// ---------------------------------------------------------------------------
__global__ __launch_bounds__(256) void k_mlp1(
    const float* __restrict__ w1, const float* __restrict__ slotsT,
    float* __restrict__ p1)
{
    __shared__ float sm[1024];
    int cc = blockIdx.x, ks = blockIdx.y, e = blockIdx.z;
    int tid = threadIdx.x;
    int k0 = ks * 64;
    int col = cc * 1024 + tid * 4;
    ((float4*)sm)[tid] = ((const float4*)(slotsT + ((size_t)e * 1024 + k0) * 16))[tid];
    __syncthreads();

    const float* wp = w1 + (size_t)e * 1024 * 4096 + (size_t)k0 * 4096 + col;
    float4 acc[16];
#pragma unroll
    for (int t = 0; t < 16; ++t) { acc[t].x = 0.f; acc[t].y = 0.f; acc[t].z = 0.f; acc[t].w = 0.f; }
#pragma unroll 8
    for (int kk = 0; kk < 64; ++kk) {
        float4 w = *(const float4*)(wp + (size_t)kk * 4096);
        const float4* q4 = (const float4*)(sm + kk * 16);
        float4 s0 = q4[0], s1 = q4[1], s2 = q4[2], s3 = q4[3];
        acc[0].x  += s0.x * w.x; acc[0].y  += s0.x * w.y; acc[0].z  += s0.x * w.z; acc[0].w  += s0.x * w.w;
        acc[1].x  += s0.y * w.x; acc[1].y  += s0.y * w.y; acc[1].z  += s0.y * w.z; acc[1].w  += s0.y * w.w;
        acc[2].x  += s0.z * w.x; acc[2].y  += s0.z * w.y; acc[2].z  += s0.z * w.z; acc[2].w  += s0.z * w.w;
        acc[3].x  += s0.w * w.x; acc[3].y  += s0.w * w.y; acc[3].z  += s0.w * w.z; acc[3].w  += s0.w * w.w;
        acc[4].x  += s1.x * w.x; acc[4].y  += s1.x * w.y; acc[4].z  += s1.x * w.z; acc[4].w  += s1.x * w.w;
        acc[5].x  += s1.y * w.x; acc[5].y  += s1.y * w.y; acc[5].z  += s1.y * w.z; acc[5].w  += s1.y * w.w;
        acc[6].x  += s1.z * w.x; acc[6].y  += s1.z * w.y; acc[6].z  += s1.z * w.z; acc[6].w  += s1.z * w.w;
        acc[7].x  += s1.w * w.x; acc[7].y  += s1.w * w.y; acc[7].z  += s1.w * w.z; acc[7].w  += s1.w * w.w;
        acc[8].x  += s2.x * w.x; acc[8].y  += s2.x * w.y; acc[8].z  += s2.x * w.z; acc[8].w  += s2.x * w.w;
        acc[9].x  += s2.y * w.x; acc[9].y  += s2.y * w.y; acc[9].z  += s2.y * w.z; acc[9].w  += s2.y * w.w;
        acc[10].x += s2.z * w.x; acc[10].y += s2.z * w.y; acc[10].z += s2.z * w.z; acc[10].w += s2.z * w.w;
        acc[11].x += s2.w * w.x; acc[11].y += s2.w * w.y; acc[11].z += s2.w * w.z; acc[11].w += s2.w * w.w;
        acc[12].x += s3.x * w.x; acc[12].y += s3.x * w.y; acc[12].z += s3.x * w.z; acc[12].w += s3.x * w.w;
        acc[13].x += s3.y * w.x; acc[13].y += s3.y * w.y; acc[13].z += s3.y * w.z; acc[13].w += s3.y * w.w;
        acc[14].x += s3.z * w.x; acc[14].y += s3.z * w.y; acc[14].z += s3.z * w.z; acc[14].w += s3.z * w.w;
        acc[15].x += s3.w * w.x; acc[15].y += s3.w * w.y; acc[15].z += s3.w * w.z; acc[15].w += s3.w * w.w;
    }
    float av0[16], av1[16], av2[16], av3[16];
#pragma unroll
    for (int t = 0; t < 16; ++t) { av0[t] = acc[t].x; av1[t] = acc[t].y; av2[t] = acc[t].z; av3[t] = acc[t].w; }
    float* op = p1 + (((size_t)ks * 8 + e) * 4096 + col) * 16;
#pragma unroll
    for (int q = 0; q < 4; ++q) {
        *(float4*)(op + 0 * 16 + q * 4) = make_float4(av0[q*4+0], av0[q*4+1], av0[q*4+2], av0[q*4+3]);
        *(float4*)(op + 1 * 16 + q * 4) = make_float4(av1[q*4+0], av1[q*4+1], av1[q*4+2], av1[q*4+3]);
        *(float4*)(op + 2 * 16 + q * 4) = make_float4(av2[q*4+0], av2[q*4+1], av2[q*4+2], av2[q*4+3]);
        *(float4*)(op + 3 * 16 + q * 4) = make_float4(av3[q*4+0], av3[q*4+1], av3[q*4+2], av3[q*4+3]);
    }
}

// ---------------------------------------------------------------------------
// D2: fused {reduce p1 (16 chunks) + bias + gelu} -> LDS, then out-partials.
// p2[ks=64][e][col=1024][t=16], hidden-chunk 64. grid (64, 8) = 512 blocks.
// ---------------------------------------------------------------------------
__global__ __launch_bounds__(256) void k_mlp2f(
    const float* __restrict__ w2, const float* __restrict__ p1,
    const float* __restrict__ b1, float* __restrict__ p2)
{
    __shared__ float sm[1024];
    int ks = blockIdx.x, e = blockIdx.y;
    int tid = threadIdx.x;
    int k0 = ks * 64;                  // hidden-col chunk [k0, k0+64)
    int col = tid * 4;

    {
        int fidx = tid;
        const float* pp = p1 + (size_t)e * 65536 + (size_t)k0 * 16 + fidx * 4;
        float4 s; s.x = 0.f; s.y = 0.f; s.z = 0.f; s.w = 0.f;
#pragma unroll
        for (int ksp = 0; ksp < 16; ++ksp) {
            float4 v = *(const float4*)(pp + (size_t)ksp * 524288);
            s.x += v.x; s.y += v.y; s.z += v.z; s.w += v.w;
        }
        int colh = k0 + (fidx >> 2);
        float bb = b1[(size_t)e * 4096 + colh];
        s.x += bb; s.y += bb; s.z += bb; s.w += bb;
        s.x = 0.5f * s.x * (1.0f + erff(s.x * 0.70710678118654752f));
        s.y = 0.5f * s.y * (1.0f + erff(s.y * 0.70710678118654752f));
        s.z = 0.5f * s.z * (1.0f + erff(s.z * 0.70710678118654752f));
        s.w = 0.5f * s.w * (1.0f + erff(s.w * 0.70710678118654752f));
        *(float4*)(&sm[fidx * 4]) = s;
    }
    __syncthreads();

    const float* wp = w2 + (size_t)e * 4096 * 1024 + (size_t)k0 * 1024 + col;
    float4 acc[16];
#pragma unroll
    for (int t = 0; t < 16; ++t) { acc[t].x = 0.f; acc[t].y = 0.f; acc[t].z = 0.f; acc[t].w = 0.f; }
#pragma unroll 8
    for (int kk = 0; kk < 64; ++kk) {
        float4 w = *(const float4*)(wp + (size_t)kk * 1024);
        const float4* q4 = (const float4*)(sm + kk * 16);
        float4 s0 = q4[0], s1 = q4[1], s2 = q4[2], s3 = q4[3];
        acc[0].x  += s0.x * w.x; acc[0].y  += s0.x * w.y; acc[0].z  += s0.x * w.z; acc[0].w  += s0.x * w.w;
        acc[1].x  += s0.y * w.x; acc[1].y  += s0.y * w.y; acc[1].z  += s0.y * w.z; acc[1].w  += s0.y * w.w;
        acc[2].x  += s0.z * w.x; acc[2].y  += s0.z * w.y; acc[2].z  += s0.z * w.z; acc[2].w  += s0.z * w.w;
        acc[3].x  += s0.w * w.x; acc[3].y  += s0.w * w.y; acc[3].z  += s0.w * w.z; acc[3].w  += s0.w * w.w;
        acc[4].x  += s1.x * w.x; acc[4].y  += s1.x * w.y; acc[4].z  += s1.x * w.z; acc[4].w  += s1.x * w.w;
        acc[5].x  += s1.y * w.x; acc[5].y  += s1.y * w.y; acc[5].z  += s1.y * w.z; acc[5].w  += s1.y * w.w;
        acc[6].x  += s1.z * w.x; acc[6].y  += s1.z * w.y; acc[6].z  += s1.z * w.z; acc[6].w  += s1.z * w.w;
        acc[7].x  += s1.w * w.x; acc[7].y  += s1.w * w.y; acc[7].z  += s1.w * w.z; acc[7].w  += s1.w * w.w;
        acc[8].x  += s2.x * w.x; acc[8].y  += s2.x * w.y; acc[8].z  += s2.x * w.z; acc[8].w  += s2.x * w.w;
        acc[9].x  += s2.y * w.x; acc[9].y  += s2.y * w.y; acc[9].z  += s2.y * w.z; acc[9].w  += s2.y * w.w;
        acc[10].x += s2.z * w.x; acc[10].y += s2.z * w.y; acc[10].z += s2.z * w.z; acc[10].w += s2.z * w.w;
        acc[11].x += s2.w * w.x; acc[11].y += s2.w * w.y; acc[11].z += s2.w * w.z; acc[11].w += s2.w * w.w;
        acc[12].x += s3.x * w.x; acc[12].y += s3.x * w.y; acc[12].z += s3.x * w.z; acc[12].w += s3.x * w.w;
        acc[13].x += s3.y * w.x; acc[13].y += s3.y * w.y; acc[13].z += s3.y * w.z; acc[13].w += s3.y * w.w;
        acc[14].x += s3.z * w.x; acc[14].y += s3.z * w.y; acc[14].z += s3.z * w.z; acc[14].w += s3.z * w.w;
        acc[15].x += s3.w * w.x; acc[15].y += s3.w * w.y; acc[15].z += s3.w * w.z; acc[15].w += s3.w * w.w;
    }
    float av0[16], av1[16], av2[16], av3[16];
#pragma unroll
    for (int t = 0; t < 16; ++t) { av0[t] = acc[t].x; av1[t] = acc[t].y; av2[t] = acc[t].z; av3[t] = acc[t].w; }
    float* op = p2 + (((size_t)ks * 8 + e) * 1024 + col) * 16;
#pragma unroll
    for (int q = 0; q < 4; ++q) {
        *(float4*)(op + 0 * 16 + q * 4) = make_float4(av0[q*4+0], av0[q*4+1], av0[q*4+2], av0[q*4+3]);
        *(float4*)(op + 1 * 16 + q * 4) = make_float4(av1[q*4+0], av1[q*4+1], av1[q*4+2], av1[q*4+3]);
        *(float4*)(op + 2 * 16 + q * 4) = make_float4(av2[q*4+0], av2[q*4+1], av2[q*4+2], av2[q*4+3]);
        *(float4*)(op + 3 * 16 + q * 4) = make_float4(av3[q*4+0], av3[q*4+1], av3[q*4+2], av3[q*4+3]);
    }
}

// ---------------------------------------------------------------------------
// D2r: co[b][j][d] = Σ_ks p2 + b2 (64 ks chunks). 8192 elems x 4/thread.
// ---------------------------------------------------------------------------
__global__ __launch_bounds__(256) void k_red2(
    const float* __restrict__ p2, const float* __restrict__ b2,
    float* __restrict__ co)
{
    int idx = blockIdx.x * 256 + threadIdx.x;    // 0..32767
    int q = idx & 3, d = (idx >> 2) & 1023, e = idx >> 12;
    const float* p = p2 + ((size_t)e * 1024 + d) * 16 + q * 4;
    float4 s; s.x = 0.f; s.y = 0.f; s.z = 0.f; s.w = 0.f;
#pragma unroll 8
    for (int ks = 0; ks < 64; ++ks) {
        float4 v = *(const float4*)(p + (size_t)ks * 131072);
        s.x += v.x; s.y += v.y; s.z += v.z; s.w += v.w;
    }
    float bb = b2[(size_t)e * 1024 + d];
    float vv[4] = { s.x + bb, s.y + bb, s.z + bb, s.w + bb };
#pragma unroll
    for (int u = 0; u < 4; ++u) {
        int t = q * 4 + u;
        int b = t >> 1, sl = t & 1;
        co[((size_t)b * 16 + e * 2 + sl) * 1024 + d] = vv[u];
    }
}

// ---------------------------------------------------------------------------
// KE: out[b,n,:] = sum_j combine[b,n,j] * co[b][j][:]. Combine tile in LDS.
// ---------------------------------------------------------------------------
__global__ __launch_bounds__(256) void k_out(
    const float* __restrict__ co, const float* __restrict__ combine,
    float* __restrict__ out)
{
    __shared__ float sm[1024];
    int b = blockIdx.y, tile = blockIdx.x;     // 64 tokens per tile
    int tid = threadIdx.x;
    ((float4*)sm)[tid] = ((const float4*)(combine + ((size_t)b * N_ + tile * 64) * 16))[tid];
    float4 cv[16];
#pragma unroll
    for (int j = 0; j < 16; ++j)
        cv[j] = ((const float4*)(co + ((size_t)b * 16 + j) * 1024))[tid];
    __syncthreads();
    float4* ob = (float4*)(out + ((size_t)b * N_ + tile * 64) * 1024) + tid;
#pragma unroll 2
    for (int it = 0; it < 64; ++it) {
        const float* cm = sm + it * 16;
        float4 acc; acc.x = 0.f; acc.y = 0.f; acc.z = 0.f; acc.w = 0.f;
#pragma unroll
        for (int j = 0; j < 16; ++j) {
            float wj = cm[j];
            acc.x += wj * cv[j].x; acc.y += wj * cv[j].y;
            acc.z += wj * cv[j].z; acc.w += wj * cv[j].w;
        }
        ob[(size_t)it * 256] = acc;
    }
}

// ---------------------------------------------------------------------------
extern "C" void kernel_launch(void* const* d_in, const int* in_sizes, int n_in,
                              void* d_out, int out_size, void* d_ws, size_t ws_size,
                              hipStream_t stream)
{
    const float* x   = (const float*)d_in[0];
    const float* phi = (const float*)d_in[2];
    const float* kg  = (const float*)d_in[3];
    const float* kb  = (const float*)d_in[4];
    const float* qg  = (const float*)d_in[5];
    const float* qb  = (const float*)d_in[6];
    const float* lng = (const float*)d_in[7];
    const float* lnb = (const float*)d_in[8];
    const float* s0  = (const float*)d_in[9];
    const float* s1  = (const float*)d_in[10];
    const float* w1  = (const float*)d_in[11];
    const float* b1  = (const float*)d_in[12];
    const float* w2  = (const float*)d_in[13];
    const float* b2  = (const float*)d_in[14];
    // occ weights d_in[15..18]: provably dead (exact-zero combine/dispatch)

    float* out = (float*)d_out;
    float* ws  = (float*)d_ws;

    float* qk       = ws;                        // 16384
    float* cj       = qk + 16384;                // 16
    float* wbuf     = cj + 16;                   // 2064
    float* combine  = wbuf + 2064;               // 524288
    float* slotsT   = combine + 524288;          // 131072
    float* co       = slotsT + 131072;           // 131072
    float* lgbuf    = co + 131072;               // 655360 (lives with spart)
    float* arenaA   = lgbuf + 655360;            // 8388608 (spart -> p1)
    float* arenaB   = arenaA + 8388608;          // 8388608 (p2)
    float* spart    = arenaA;
    float* p1       = arenaA;
    float* p2       = arenaB;

    k_prep        <<<dim3(17),        dim3(64),  0, stream>>>(phi, qg, qb, lng, lnb, kg, kb, qk, cj, wbuf);
    k_fused       <<<dim3(512),       dim3(512), 0, stream>>>(x, qk, wbuf, cj, s0, lgbuf, spart);
    k_epi         <<<dim3(512),       dim3(64),  0, stream>>>(lgbuf, cj, wbuf, s1, combine);
    k_slots_reduce<<<dim3(16, 8),     dim3(256), 0, stream>>>(spart, slotsT);
    k_mlp1        <<<dim3(4, 16, 8),  dim3(256), 0, stream>>>(w1, slotsT, p1);
    k_mlp2f       <<<dim3(64, 8),     dim3(256), 0, stream>>>(w2, p1, b1, p2);
    k_red2        <<<dim3(128),       dim3(256), 0, stream>>>(p2, b2, co);
    k_out         <<<dim3(64, 8),     dim3(256), 0, stream>>>(co, combine, out);
}

// Round 18
// 213.565 us; speedup vs baseline: 1.2214x; 1.0024x over previous
//
#include <hip/hip_runtime.h>
#include <hip/hip_bf16.h>

#define B_ 8
#define N_ 4096
#define D_ 1024

typedef __attribute__((ext_vector_type(8))) short short8_t;
typedef __attribute__((ext_vector_type(4))) float f32x4;

__device__ __forceinline__ unsigned short f2bf(float f) {
    union { float f; unsigned int u; } v; v.f = f;
    unsigned int r = v.u + 0x7FFF + ((v.u >> 16) & 1);   // RNE
    return (unsigned short)(r >> 16);
}

// ---------------------------------------------------------------------------
// K0: prep. blocks 0..15: q = l2norm(layernorm(phi*qg+qb)); qkb[r] = bf16(q⊙kg),
//     cj[r] = Σ q·kb.  block 16: wbuf = {kg², 2·kg·kb, Σkb²}.
// ---------------------------------------------------------------------------
__global__ __launch_bounds__(64) void k_prep(
    const float* __restrict__ phi, const float* __restrict__ qg, const float* __restrict__ qb,
    const float* __restrict__ lng, const float* __restrict__ lnb,
    const float* __restrict__ kg, const float* __restrict__ kb,
    unsigned short* __restrict__ qkb, float* __restrict__ cj, float* __restrict__ wbuf)
{
    int r = blockIdx.x;        // 0..16
    int lane = threadIdx.x;    // 0..63
    if (r == 16) {
        float cacc = 0.f;
#pragma unroll
        for (int c = 0; c < 16; ++c) {
            int i = c * 64 + lane;
            float g = kg[i], b = kb[i];
            wbuf[i] = g * g;
            wbuf[1024 + i] = 2.0f * g * b;
            cacc += b * b;
        }
#pragma unroll
        for (int m = 32; m; m >>= 1) cacc += __shfl_xor(cacc, m);
        if (lane == 0) wbuf[2048] = cacc;
        return;
    }
    const float* pr = phi + (size_t)r * D_;
    float v[16];
    float s1 = 0.f;
#pragma unroll
    for (int c = 0; c < 16; ++c) {
        int i = c * 64 + lane;
        v[c] = pr[i] * qg[i] + qb[i];
        s1 += v[c];
    }
#pragma unroll
    for (int m = 32; m; m >>= 1) s1 += __shfl_xor(s1, m);
    float mu = s1 * (1.0f / D_);
    float s2 = 0.f;
#pragma unroll
    for (int c = 0; c < 16; ++c) { float dd = v[c] - mu; s2 += dd * dd; }
#pragma unroll
    for (int m = 32; m; m >>= 1) s2 += __shfl_xor(s2, m);
    float var = s2 * (1.0f / D_);
    float inv = 1.0f / sqrtf(var + 1e-5f);
    float u[16];
    float s3 = 0.f;
#pragma unroll
    for (int c = 0; c < 16; ++c) {
        int i = c * 64 + lane;
        u[c] = (v[c] - mu) * inv * lng[i] + lnb[i];
        s3 += u[c] * u[c];
    }
#pragma unroll
    for (int m = 32; m; m >>= 1) s3 += __shfl_xor(s3, m);
    float rn = 1.0f / (sqrtf(s3) + 1e-6f);
    float cacc = 0.f;
#pragma unroll
    for (int c = 0; c < 16; ++c) {
        int i = c * 64 + lane;
        float qv = u[c] * rn;
        qkb[(size_t)r * D_ + i] = f2bf(qv * kg[i]);
        cacc += qv * kb[i];
    }
#pragma unroll
    for (int m = 32; m; m >>= 1) cacc += __shfl_xor(cacc, m);
    if (lane == 0) cj[r] = cacc;
}

// ---------------------------------------------------------------------------
// K1: FUSED logits (bf16 MFMA) + softmax-dispatch + slot-partials.
// 512 threads (8 waves), 64 tokens/block, 512 blocks (2 blocks/CU).
// Wave wv: token-tile wt=wv&3 (16 tokens), k-half kh=wv>>2 (512 d each).
// A = x fragment (f32 loads -> v_cvt_pk_bf16_f32), B = qkb from L2 (bf16).
// One mfma_f32_16x16x32_bf16 per k-step; C[16 tok][16 j] complete in regs
// (col=lane&15=j, row=(lane>>4)*4+reg=token). Weighted-norm term rides in
// f32 on the same x values. k-halves merged via LDS. Phase 2 = round-13
// proven f32 slot-partials (J-half split, acc2[8]).
// ---------------------------------------------------------------------------
__global__ __launch_bounds__(512) void k_fused(
    const float* __restrict__ x, const unsigned short* __restrict__ qkb,
    const float* __restrict__ wbuf, const float* __restrict__ cj,
    const float* __restrict__ s0p,
    float* __restrict__ lgbuf, float* __restrict__ spart)
{
    __shared__ float smem[4288];
    float* part = smem;            // [2 kh][64 tok][16 j] = 2048
    float* nrmp = smem + 2048;     // [2 kh][64 tok] = 128
    float* sums = smem + 2176;     // [64 tok][17] = 1088
    float* disp = smem + 3264;     // [64 tok][16] = 1024

    int tid = threadIdx.x;
    int tok0 = blockIdx.x * 64;
    int wv = tid >> 6;             // 0..7
    int lane = tid & 63;
    int wt = wv & 3;               // token tile
    int kh = wv >> 2;              // k half
    int am = lane & 15;            // A row (token) AND B row (j)
    int kg = lane >> 4;            // k-group 0..3

    const float* xrow = x + (size_t)(tok0 + wt * 16 + am) * D_ + kh * 512 + kg * 8;
    const unsigned short* qrow = qkb + (size_t)am * 1024 + kh * 512 + kg * 8;
    const float* w2row = wbuf + kh * 512 + kg * 8;
    const float* w1row = wbuf + 1024 + kh * 512 + kg * 8;

    f32x4 acc = {0.f, 0.f, 0.f, 0.f};
    float nrm = 0.f;
#pragma unroll 2
    for (int ks = 0; ks < 16; ++ks) {
        int off = ks * 32;
        float4 a0  = *(const float4*)(xrow + off);
        float4 a1  = *(const float4*)(xrow + off + 4);
        float4 w2a = *(const float4*)(w2row + off);
        float4 w2b = *(const float4*)(w2row + off + 4);
        float4 w1a = *(const float4*)(w1row + off);
        float4 w1b = *(const float4*)(w1row + off + 4);
        nrm += (w2a.x * a0.x + w1a.x) * a0.x + (w2a.y * a0.y + w1a.y) * a0.y
             + (w2a.z * a0.z + w1a.z) * a0.z + (w2a.w * a0.w + w1a.w) * a0.w
             + (w2b.x * a1.x + w1b.x) * a1.x + (w2b.y * a1.y + w1b.y) * a1.y
             + (w2b.z * a1.z + w1b.z) * a1.z + (w2b.w * a1.w + w1b.w) * a1.w;
        int p0, p1, p2, p3;
        asm("v_cvt_pk_bf16_f32 %0, %1, %2" : "=v"(p0) : "v"(a0.x), "v"(a0.y));
        asm("v_cvt_pk_bf16_f32 %0, %1, %2" : "=v"(p1) : "v"(a0.z), "v"(a0.w));
        asm("v_cvt_pk_bf16_f32 %0, %1, %2" : "=v"(p2) : "v"(a1.x), "v"(a1.y));
        asm("v_cvt_pk_bf16_f32 %0, %1, %2" : "=v"(p3) : "v"(a1.z), "v"(a1.w));
        union { int i[4]; short8_t s; } ua;
        ua.i[0] = p0; ua.i[1] = p1; ua.i[2] = p2; ua.i[3] = p3;
        short8_t bv = *(const short8_t*)(qrow + off);
        acc = __builtin_amdgcn_mfma_f32_16x16x32_bf16(ua.s, bv, acc, 0, 0, 0);
    }
    // norm: reduce across k-groups (lanes at xor 16, 32 share token am)
    nrm += __shfl_xor(nrm, 16);
    nrm += __shfl_xor(nrm, 32);

    // store per-k-half partials (C/D layout: col=am=j, row=kg*4+r=token)
#pragma unroll
    for (int r = 0; r < 4; ++r)
        part[(kh * 64 + wt * 16 + kg * 4 + r) * 16 + am] = acc[r];
    if (kg == 0) nrmp[kh * 64 + wt * 16 + am] = nrm;
    __syncthreads();

    // merge k-halves -> sums + lgbuf
#pragma unroll
    for (int it = 0; it < 3; ++it) {
        int idx = tid + it * 512;
        if (idx < 1088) {
            int t = idx / 17, v = idx - t * 17;
            float sv = (v < 16) ? (part[t * 16 + v] + part[1024 + t * 16 + v])
                                : (nrmp[t] + nrmp[64 + t]);
            sums[idx] = sv;
            lgbuf[(size_t)(tok0 + t) * 20 + v] = sv;
        }
    }
    __syncthreads();

    // softmax-dispatch (entmax in k_epi): one thread per token
    if (tid < 64) {
        const float* sp = sums + tid * 17;
        float ss = sp[16] + wbuf[2048];
        float rn = 1.0f / (sqrtf(ss) + 1e-6f);
        float inv0 = 1.0f / s0p[0];
        float lg[16];
#pragma unroll
        for (int j = 0; j < 16; ++j) lg[j] = (sp[j] + cj[j]) * rn;
        float dsp[16];
#pragma unroll
        for (int sl = 0; sl < 2; ++sl) {
            float a[8], m = -1e30f;
#pragma unroll
            for (int ee = 0; ee < 8; ++ee) { a[ee] = lg[2 * ee + sl] * inv0; m = fmaxf(m, a[ee]); }
            float den = 0.f;
#pragma unroll
            for (int ee = 0; ee < 8; ++ee) { a[ee] = expf(a[ee] - m); den += a[ee]; }
            float r = 1.0f / den;
#pragma unroll
            for (int ee = 0; ee < 8; ++ee) dsp[2 * ee + sl] = a[ee] * r;
        }
#pragma unroll
        for (int q4i = 0; q4i < 4; ++q4i)
            *(float4*)(&disp[tid * 16 + q4i * 4]) =
                make_float4(dsp[q4i * 4 + 0], dsp[q4i * 4 + 1], dsp[q4i * 4 + 2], dsp[q4i * 4 + 3]);
    }
    __syncthreads();

    // phase 2: slot partials, J-HALF per thread-half (x L2-warm)
    int th = tid >> 8;             // 0/1: experts [th*8, th*8+8)
    int cix = tid & 255;           // float4 column of d
    const float* xp = x + (size_t)tok0 * D_ + cix * 4;
    float4 acc2[8];
#pragma unroll
    for (int j = 0; j < 8; ++j) { acc2[j].x = 0.f; acc2[j].y = 0.f; acc2[j].z = 0.f; acc2[j].w = 0.f; }
#pragma unroll 8
    for (int n = 0; n < 64; ++n) {
        float4 xv = *(const float4*)(xp + (size_t)n * D_);
        const float4* q4 = (const float4*)(disp + n * 16 + th * 8);
        float4 s0 = q4[0], s1 = q4[1];
        acc2[0].x += s0.x * xv.x; acc2[0].y += s0.x * xv.y; acc2[0].z += s0.x * xv.z; acc2[0].w += s0.x * xv.w;
        acc2[1].x += s0.y * xv.x; acc2[1].y += s0.y * xv.y; acc2[1].z += s0.y * xv.z; acc2[1].w += s0.y * xv.w;
        acc2[2].x += s0.z * xv.x; acc2[2].y += s0.z * xv.y; acc2[2].z += s0.z * xv.z; acc2[2].w += s0.z * xv.w;
        acc2[3].x += s0.w * xv.x; acc2[3].y += s0.w * xv.y; acc2[3].z += s0.w * xv.z; acc2[3].w += s0.w * xv.w;
        acc2[4].x += s1.x * xv.x; acc2[4].y += s1.x * xv.y; acc2[4].z += s1.x * xv.z; acc2[4].w += s1.x * xv.w;
        acc2[5].x += s1.y * xv.x; acc2[5].y += s1.y * xv.y; acc2[5].z += s1.y * xv.z; acc2[5].w += s1.y * xv.w;
        acc2[6].x += s1.z * xv.x; acc2[6].y += s1.z * xv.y; acc2[6].z += s1.z * xv.z; acc2[6].w += s1.z * xv.w;
        acc2[7].x += s1.w * xv.x; acc2[7].y += s1.w * xv.y; acc2[7].z += s1.w * xv.z; acc2[7].w += s1.w * xv.w;
    }
    float* op = spart + ((size_t)blockIdx.x * 16 + th * 8) * 1024 + cix * 4;
#pragma unroll
    for (int j = 0; j < 8; ++j)
        *(float4*)(op + (size_t)j * 1024) = acc2[j];
}

// ---------------------------------------------------------------------------
// K1b: per-token entmax15 epilogue -> combine only.
// ---------------------------------------------------------------------------
__global__ __launch_bounds__(64) void k_epi(
    const float* __restrict__ lgbuf, const float* __restrict__ cj,
    const float* __restrict__ wbuf, const float* __restrict__ s1p,
    float* __restrict__ combine)
{
    int tok = blockIdx.x * 64 + threadIdx.x;
    const float* lp = lgbuf + (size_t)tok * 20;
    float s[17];
    float4 q0 = *(const float4*)(lp + 0);
    float4 q1 = *(const float4*)(lp + 4);
    float4 q2 = *(const float4*)(lp + 8);
    float4 q3 = *(const float4*)(lp + 12);
    s[0] = q0.x; s[1] = q0.y; s[2] = q0.z; s[3] = q0.w;
    s[4] = q1.x; s[5] = q1.y; s[6] = q1.z; s[7] = q1.w;
    s[8] = q2.x; s[9] = q2.y; s[10] = q2.z; s[11] = q2.w;
    s[12] = q3.x; s[13] = q3.y; s[14] = q3.z; s[15] = q3.w;
    s[16] = lp[16];

    float ss = s[16] + wbuf[2048];
    float rn = 1.0f / (sqrtf(ss) + 1e-6f);
    float inv1h = 0.5f / s1p[0];
    float lg[16];
#pragma unroll
    for (int j = 0; j < 16; ++j) lg[j] = (s[j] + cj[j]) * rn;

    float z[16], zmax = -1e30f;
#pragma unroll
    for (int j = 0; j < 16; ++j) { z[j] = lg[j] * inv1h; zmax = fmaxf(zmax, z[j]); }
#pragma unroll
    for (int j = 0; j < 16; ++j) z[j] -= zmax;
    float zsr[16];
#pragma unroll
    for (int j = 0; j < 16; ++j) zsr[j] = z[j];
#pragma unroll
    for (int rr = 0; rr < 16; ++rr) {
#pragma unroll
        for (int jj = (rr & 1); jj + 1 < 16; jj += 2) {
            float aa = zsr[jj], bb = zsr[jj + 1];
            zsr[jj] = fmaxf(aa, bb);
            zsr[jj + 1] = fminf(aa, bb);
        }
    }
    float cs = 0.f, css = 0.f, tau_star = 0.f;
#pragma unroll
    for (int kk = 1; kk <= 16; ++kk) {
        cs += zsr[kk - 1];
        css += zsr[kk - 1] * zsr[kk - 1];
        float fk = (float)kk;
        float mean = cs / fk, msq = css / fk;
        float ssv = fk * (msq - mean * mean);
        float delta = fmaxf((1.0f - ssv) / fk, 1e-12f);
        float tau = mean - sqrtf(delta);
        tau_star = (tau <= zsr[kk - 1]) ? tau : tau_star;
    }
    float4* cw = (float4*)(combine + (size_t)tok * 16);
#pragma unroll
    for (int q4i = 0; q4i < 4; ++q4i) {
        float4 cv;
        float t0 = fmaxf(z[q4i * 4 + 0] - tau_star, 0.f);
        float t1 = fmaxf(z[q4i * 4 + 1] - tau_star, 0.f);
        float t2 = fmaxf(z[q4i * 4 + 2] - tau_star, 0.f);
        float t3 = fmaxf(z[q4i * 4 + 3] - tau_star, 0.f);
        cv.x = t0 * t0; cv.y = t1 * t1; cv.z = t2 * t2; cv.w = t3 * t3;
        cw[q4i] = cv;
    }
}

// ---------------------------------------------------------------------------
// K2c: coalesced reduce over 64 nc chunks. slotsT[e][k][t] (t=b*2+s, j=e*2+s).
// ---------------------------------------------------------------------------
__global__ __launch_bounds__(256) void k_slots_reduce(
    const float* __restrict__ spart, float* __restrict__ slotsT)
{
    int j = blockIdx.x, b = blockIdx.y;
    int tid = threadIdx.x;
    const float* p = spart + ((size_t)(b * 64) * 16 + j) * 1024 + tid * 4;
    float4 s; s.x = 0.f; s.y = 0.f; s.z = 0.f; s.w = 0.f;
#pragma unroll 8
    for (int nc = 0; nc < 64; ++nc) {
        float4 v = *(const float4*)(p + (size_t)nc * 16384);
        s.x += v.x; s.y += v.y; s.z += v.z; s.w += v.w;
    }
    int e = j >> 1, sl = j & 1;
    int t = b * 2 + sl;
    float* o = slotsT + ((size_t)e * 1024 + tid * 4) * 16 + t;
    o[0] = s.x; o[16] = s.y; o[32] = s.z; o[48] = s.w;
}

// ---------------------------------------------------------------------------
// D1: split-K h-partials. p1[ks=16][e][col=4096][t=16], K-chunk 64.
// ---------------------------------------------------------------------------
__global__ __launch_bounds__(256) void k_mlp1(
    const float* __restrict__ w1, const float* __restrict__ slotsT,
    float* __restrict__ p1)
{
    __shared__ float sm[1024];
    int cc = blockIdx.x, ks = blockIdx.y, e = blockIdx.z;
    int tid = threadIdx.x;
    int k0 = ks * 64;
    int col = cc * 1024 + tid * 4;
    ((float4*)sm)[tid] = ((const float4*)(slotsT + ((size_t)e * 1024 + k0) * 16))[tid];
    __syncthreads();

    const float* wp = w1 + (size_t)e * 1024 * 4096 + (size_t)k0 * 4096 + col;
    float4 acc[16];
#pragma unroll
    for (int t = 0; t < 16; ++t) { acc[t].x = 0.f; acc[t].y = 0.f; acc[t].z = 0.f; acc[t].w = 0.f; }
#pragma unroll 8
    for (int kk = 0; kk < 64; ++kk) {
        float4 w = *(const float4*)(wp + (size_t)kk * 4096);
        const float4* q4 = (const float4*)(sm + kk * 16);
        float4 s0 = q4[0], s1 = q4[1], s2 = q4[2], s3 = q4[3];
        acc[0].x  += s0.x * w.x; acc[0].y  += s0.x * w.y; acc[0].z  += s0.x * w.z; acc[0].w  += s0.x * w.w;
        acc[1].x  += s0.y * w.x; acc[1].y  += s0.y * w.y; acc[1].z  += s0.y * w.z; acc[1].w  += s0.y * w.w;
        acc[2].x  += s0.z * w.x; acc[2].y  += s0.z * w.y; acc[2].z  += s0.z * w.z; acc[2].w  += s0.z * w.w;
        acc[3].x  += s0.w * w.x; acc[3].y  += s0.w * w.y; acc[3].z  += s0.w * w.z; acc[3].w  += s0.w * w.w;
        acc[4].x  += s1.x * w.x; acc[4].y  += s1.x * w.y; acc[4].z  += s1.x * w.z; acc[4].w  += s1.x * w.w;
        acc[5].x  += s1.y * w.x; acc[5].y  += s1.y * w.y; acc[5].z  += s1.y * w.z; acc[5].w  += s1.y * w.w;
        acc[6].x  += s1.z * w.x; acc[6].y  += s1.z * w.y; acc[6].z  += s1.z * w.z; acc[6].w  += s1.z * w.w;
        acc[7].x  += s1.w * w.x; acc[7].y  += s1.w * w.y; acc[7].z  += s1.w * w.z; acc[7].w  += s1.w * w.w;
        acc[8].x  += s2.x * w.x; acc[8].y  += s2.x * w.y; acc[8].z  += s2.x * w.z; acc[8].w  += s2.x * w.w;
        acc[9].x  += s2.y * w.x; acc[9].y  += s2.y * w.y; acc[9].z  += s2.y * w.z; acc[9].w  += s2.y * w.w;
        acc[10].x += s2.z * w.x; acc[10].y += s2.z * w.y; acc[10].z += s2.z * w.z; acc[10].w += s2.z * w.w;
        acc[11].x += s2.w * w.x; acc[11].y += s2.w * w.y; acc[11].z += s2.w * w.z; acc[11].w += s2.w * w.w;
        acc[12].x += s3.x * w.x; acc[12].y += s3.x * w.y; acc[12].z += s3.x * w.z; acc[12].w += s3.x * w.w;
        acc[13].x += s3.y * w.x; acc[13].y += s3.y * w.y; acc[13].z += s3.y * w.z; acc[13].w += s3.y * w.w;
        acc[14].x += s3.z * w.x; acc[14].y += s3.z * w.y; acc[14].z += s3.z * w.z; acc[14].w += s3.z * w.w;
        acc[15].x += s3.w * w.x; acc[15].y += s3.w * w.y; acc[15].z += s3.w * w.z; acc[15].w += s3.w * w.w;
    }
    float av0[16], av1[16], av2[16], av3[16];
#pragma unroll
    for (int t = 0; t < 16; ++t) { av0[t] = acc[t].x; av1[t] = acc[t].y; av2[t] = acc[t].z; av3[t] = acc[t].w; }
    float* op = p1 + (((size_t)ks * 8 + e) * 4096 + col) * 16;
#pragma unroll
    for (int q = 0; q < 4; ++q) {
        *(float4*)(op + 0 * 16 + q * 4) = make_float4(av0[q*4+0], av0[q*4+1], av0[q*4+2], av0[q*4+3]);
        *(float4*)(op + 1 * 16 + q * 4) = make_float4(av1[q*4+0], av1[q*4+1], av1[q*4+2], av1[q*4+3]);
        *(float4*)(op + 2 * 16 + q * 4) = make_float4(av2[q*4+0], av2[q*4+1], av2[q*4+2], av2[q*4+3]);
        *(float4*)(op + 3 * 16 + q * 4) = make_float4(av3[q*4+0], av3[q*4+1], av3[q*4+2], av3[q*4+3]);
    }
}

// ---------------------------------------------------------------------------
// D2: fused {reduce p1 (16 chunks) + bias + gelu} -> LDS, then out-partials.
// p2[ks=64][e][col=1024][t=16], hidden-chunk 64. grid (64, 8) = 512 blocks.
// ---------------------------------------------------------------------------
__global__ __launch_bounds__(256) void k_mlp2f(
    const float* __restrict__ w2, const float* __restrict__ p1,
    const float* __restrict__ b1, float* __restrict__ p2)
{
    __shared__ float sm[1024];
    int ks = blockIdx.x, e = blockIdx.y;
    int tid = threadIdx.x;
    int k0 = ks * 64;                  // hidden-col chunk [k0, k0+64)
    int col = tid * 4;

    {
        int fidx = tid;
        const float* pp = p1 + (size_t)e * 65536 + (size_t)k0 * 16 + fidx * 4;
        float4 s; s.x = 0.f; s.y = 0.f; s.z = 0.f; s.w = 0.f;
#pragma unroll
        for (int ksp = 0; ksp < 16; ++ksp) {
            float4 v = *(const float4*)(pp + (size_t)ksp * 524288);
            s.x += v.x; s.y += v.y; s.z += v.z; s.w += v.w;
        }
        int colh = k0 + (fidx >> 2);
        float bb = b1[(size_t)e * 4096 + colh];
        s.x += bb; s.y += bb; s.z += bb; s.w += bb;
        s.x = 0.5f * s.x * (1.0f + erff(s.x * 0.70710678118654752f));
        s.y = 0.5f * s.y * (1.0f + erff(s.y * 0.70710678118654752f));
        s.z = 0.5f * s.z * (1.0f + erff(s.z * 0.70710678118654752f));
        s.w = 0.5f * s.w * (1.0f + erff(s.w * 0.70710678118654752f));
        *(float4*)(&sm[fidx * 4]) = s;
    }
    __syncthreads();

    const float* wp = w2 + (size_t)e * 4096 * 1024 + (size_t)k0 * 1024 + col;
    float4 acc[16];
#pragma unroll
    for (int t = 0; t < 16; ++t) { acc[t].x = 0.f; acc[t].y = 0.f; acc[t].z = 0.f; acc[t].w = 0.f; }
#pragma unroll 8
    for (int kk = 0; kk < 64; ++kk) {
        float4 w = *(const float4*)(wp + (size_t)kk * 1024);
        const float4* q4 = (const float4*)(sm + kk * 16);
        float4 s0 = q4[0], s1 = q4[1], s2 = q4[2], s3 = q4[3];
        acc[0].x  += s0.x * w.x; acc[0].y  += s0.x * w.y; acc[0].z  += s0.x * w.z; acc[0].w  += s0.x * w.w;
        acc[1].x  += s0.y * w.x; acc[1].y  += s0.y * w.y; acc[1].z  += s0.y * w.z; acc[1].w  += s0.y * w.w;
        acc[2].x  += s0.z * w.x; acc[2].y  += s0.z * w.y; acc[2].z  += s0.z * w.z; acc[2].w  += s0.z * w.w;
        acc[3].x  += s0.w * w.x; acc[3].y  += s0.w * w.y; acc[3].z  += s0.w * w.z; acc[3].w  += s0.w * w.w;
        acc[4].x  += s1.x * w.x; acc[4].y  += s1.x * w.y; acc[4].z  += s1.x * w.z; acc[4].w  += s1.x * w.w;
        acc[5].x  += s1.y * w.x; acc[5].y  += s1.y * w.y; acc[5].z  += s1.y * w.z; acc[5].w  += s1.y * w.w;
        acc[6].x  += s1.z * w.x; acc[6].y  += s1.z * w.y; acc[6].z  += s1.z * w.z; acc[6].w  += s1.z * w.w;
        acc[7].x  += s1.w * w.x; acc[7].y  += s1.w * w.y; acc[7].z  += s1.w * w.z; acc[7].w  += s1.w * w.w;
        acc[8].x  += s2.x * w.x; acc[8].y  += s2.x * w.y; acc[8].z  += s2.x * w.z; acc[8].w  += s2.x * w.w;
        acc[9].x  += s2.y * w.x; acc[9].y  += s2.y * w.y; acc[9].z  += s2.y * w.z; acc[9].w  += s2.y * w.w;
        acc[10].x += s2.z * w.x; acc[10].y += s2.z * w.y; acc[10].z += s2.z * w.z; acc[10].w += s2.z * w.w;
        acc[11].x += s2.w * w.x; acc[11].y += s2.w * w.y; acc[11].z += s2.w * w.z; acc[11].w += s2.w * w.w;
        acc[12].x += s3.x * w.x; acc[12].y += s3.x * w.y; acc[12].z += s3.x * w.z; acc[12].w += s3.x * w.w;
        acc[13].x += s3.y * w.x; acc[13].y += s3.y * w.y; acc[13].z += s3.y * w.z; acc[13].w += s3.y * w.w;
        acc[14].x += s3.z * w.x; acc[14].y += s3.z * w.y; acc[14].z += s3.z * w.z; acc[14].w += s3.z * w.w;
        acc[15].x += s3.w * w.x; acc[15].y += s3.w * w.y; acc[15].z += s3.w * w.z; acc[15].w += s3.w * w.w;
    }
    float av0[16], av1[16], av2[16], av3[16];
#pragma unroll
    for (int t = 0; t < 16; ++t) { av0[t] = acc[t].x; av1[t] = acc[t].y; av2[t] = acc[t].z; av3[t] = acc[t].w; }
    float* op = p2 + (((size_t)ks * 8 + e) * 1024 + col) * 16;
#pragma unroll
    for (int q = 0; q < 4; ++q) {
        *(float4*)(op + 0 * 16 + q * 4) = make_float4(av0[q*4+0], av0[q*4+1], av0[q*4+2], av0[q*4+3]);
        *(float4*)(op + 1 * 16 + q * 4) = make_float4(av1[q*4+0], av1[q*4+1], av1[q*4+2], av1[q*4+3]);
        *(float4*)(op + 2 * 16 + q * 4) = make_float4(av2[q*4+0], av2[q*4+1], av2[q*4+2], av2[q*4+3]);
        *(float4*)(op + 3 * 16 + q * 4) = make_float4(av3[q*4+0], av3[q*4+1], av3[q*4+2], av3[q*4+3]);
    }
}

// ---------------------------------------------------------------------------
// D2r: co[b][j][d] = Σ_ks p2 + b2 (64 ks chunks). 8192 elems x 4/thread.
// ---------------------------------------------------------------------------
__global__ __launch_bounds__(256) void k_red2(
    const float* __restrict__ p2, const float* __restrict__ b2,
    float* __restrict__ co)
{
    int idx = blockIdx.x * 256 + threadIdx.x;    // 0..32767
    int q = idx & 3, d = (idx >> 2) & 1023, e = idx >> 12;
    const float* p = p2 + ((size_t)e * 1024 + d) * 16 + q * 4;
    float4 s; s.x = 0.f; s.y = 0.f; s.z = 0.f; s.w = 0.f;
#pragma unroll 8
    for (int ks = 0; ks < 64; ++ks) {
        float4 v = *(const float4*)(p + (size_t)ks * 131072);
        s.x += v.x; s.y += v.y; s.z += v.z; s.w += v.w;
    }
    float bb = b2[(size_t)e * 1024 + d];
    float vv[4] = { s.x + bb, s.y + bb, s.z + bb, s.w + bb };
#pragma unroll
    for (int u = 0; u < 4; ++u) {
        int t = q * 4 + u;
        int b = t >> 1, sl = t & 1;
        co[((size_t)b * 16 + e * 2 + sl) * 1024 + d] = vv[u];
    }
}

// ---------------------------------------------------------------------------
// KE: out[b,n,:] = sum_j combine[b,n,j] * co[b][j][:]. Combine tile in LDS.
// ---------------------------------------------------------------------------
__global__ __launch_bounds__(256) void k_out(
    const float* __restrict__ co, const float* __restrict__ combine,
    float* __restrict__ out)
{
    __shared__ float sm[1024];
    int b = blockIdx.y, tile = blockIdx.x;     // 64 tokens per tile
    int tid = threadIdx.x;
    ((float4*)sm)[tid] = ((const float4*)(combine + ((size_t)b * N_ + tile * 64) * 16))[tid];
    float4 cv[16];
#pragma unroll
    for (int j = 0; j < 16; ++j)
        cv[j] = ((const float4*)(co + ((size_t)b * 16 + j) * 1024))[tid];
    __syncthreads();
    float4* ob = (float4*)(out + ((size_t)b * N_ + tile * 64) * 1024) + tid;
#pragma unroll 2
    for (int it = 0; it < 64; ++it) {
        const float* cm = sm + it * 16;
        float4 acc; acc.x = 0.f; acc.y = 0.f; acc.z = 0.f; acc.w = 0.f;
#pragma unroll
        for (int j = 0; j < 16; ++j) {
            float wj = cm[j];
            acc.x += wj * cv[j].x; acc.y += wj * cv[j].y;
            acc.z += wj * cv[j].z; acc.w += wj * cv[j].w;
        }
        ob[(size_t)it * 256] = acc;
    }
}

// ---------------------------------------------------------------------------
extern "C" void kernel_launch(void* const* d_in, const int* in_sizes, int n_in,
                              void* d_out, int out_size, void* d_ws, size_t ws_size,
                              hipStream_t stream)
{
    const float* x   = (const float*)d_in[0];
    const float* phi = (const float*)d_in[2];
    const float* kg  = (const float*)d_in[3];
    const float* kb  = (const float*)d_in[4];
    const float* qg  = (const float*)d_in[5];
    const float* qb  = (const float*)d_in[6];
    const float* lng = (const float*)d_in[7];
    const float* lnb = (const float*)d_in[8];
    const float* s0  = (const float*)d_in[9];
    const float* s1  = (const float*)d_in[10];
    const float* w1  = (const float*)d_in[11];
    const float* b1  = (const float*)d_in[12];
    const float* w2  = (const float*)d_in[13];
    const float* b2  = (const float*)d_in[14];
    // occ weights d_in[15..18]: provably dead (exact-zero combine/dispatch)

    float* out = (float*)d_out;
    float* ws  = (float*)d_ws;

    unsigned short* qkb = (unsigned short*)ws;   // 16384 shorts = 8192 floats
    float* cj       = ws + 8192;                 // 16
    float* wbuf     = cj + 16;                   // 2064
    float* combine  = wbuf + 2064;               // 524288
    float* slotsT   = combine + 524288;          // 131072
    float* co       = slotsT + 131072;           // 131072
    float* lgbuf    = co + 131072;               // 655360 (lives with spart)
    float* arenaA   = lgbuf + 655360;            // 8388608 (spart -> p1)
    float* arenaB   = arenaA + 8388608;          // 8388608 (p2)
    float* spart    = arenaA;
    float* p1       = arenaA;
    float* p2       = arenaB;

    k_prep        <<<dim3(17),        dim3(64),  0, stream>>>(phi, qg, qb, lng, lnb, kg, kb, qkb, cj, wbuf);
    k_fused       <<<dim3(512),       dim3(512), 0, stream>>>(x, qkb, wbuf, cj, s0, lgbuf, spart);
    k_epi         <<<dim3(512),       dim3(64),  0, stream>>>(lgbuf, cj, wbuf, s1, combine);
    k_slots_reduce<<<dim3(16, 8),     dim3(256), 0, stream>>>(spart, slotsT);
    k_mlp1        <<<dim3(4, 16, 8),  dim3(256), 0, stream>>>(w1, slotsT, p1);
    k_mlp2f       <<<dim3(64, 8),     dim3(256), 0, stream>>>(w2, p1, b1, p2);
    k_red2        <<<dim3(128),       dim3(256), 0, stream>>>(p2, b2, co);
    k_out         <<<dim3(64, 8),     dim3(256), 0, stream>>>(co, combine, out);
}

// Round 19
// 206.952 us; speedup vs baseline: 1.2605x; 1.0320x over previous
//
#include <hip/hip_runtime.h>
#include <hip/hip_bf16.h>

#define B_ 8
#define N_ 4096
#define D_ 1024

typedef __attribute__((ext_vector_type(8))) short short8_t;
typedef __attribute__((ext_vector_type(4))) float f32x4;

__device__ __forceinline__ unsigned short f2bf(float f) {
    union { float f; unsigned int u; } v; v.f = f;
    unsigned int r = v.u + 0x7FFF + ((v.u >> 16) & 1);   // RNE
    return (unsigned short)(r >> 16);
}

// ---------------------------------------------------------------------------
// K0: prep. blocks 0..15: q = l2norm(layernorm(phi*qg+qb)); qkb[r] = bf16(q⊙kg),
//     cj[r] = Σ q·kb.  block 16: wbuf = {kg², 2·kg·kb, Σkb²}.
// ---------------------------------------------------------------------------
__global__ __launch_bounds__(64) void k_prep(
    const float* __restrict__ phi, const float* __restrict__ qg, const float* __restrict__ qb,
    const float* __restrict__ lng, const float* __restrict__ lnb,
    const float* __restrict__ kg, const float* __restrict__ kb,
    unsigned short* __restrict__ qkb, float* __restrict__ cj, float* __restrict__ wbuf)
{
    int r = blockIdx.x;        // 0..16
    int lane = threadIdx.x;    // 0..63
    if (r == 16) {
        float cacc = 0.f;
#pragma unroll
        for (int c = 0; c < 16; ++c) {
            int i = c * 64 + lane;
            float g = kg[i], b = kb[i];
            wbuf[i] = g * g;
            wbuf[1024 + i] = 2.0f * g * b;
            cacc += b * b;
        }
#pragma unroll
        for (int m = 32; m; m >>= 1) cacc += __shfl_xor(cacc, m);
        if (lane == 0) wbuf[2048] = cacc;
        return;
    }
    const float* pr = phi + (size_t)r * D_;
    float v[16];
    float s1 = 0.f;
#pragma unroll
    for (int c = 0; c < 16; ++c) {
        int i = c * 64 + lane;
        v[c] = pr[i] * qg[i] + qb[i];
        s1 += v[c];
    }
#pragma unroll
    for (int m = 32; m; m >>= 1) s1 += __shfl_xor(s1, m);
    float mu = s1 * (1.0f / D_);
    float s2 = 0.f;
#pragma unroll
    for (int c = 0; c < 16; ++c) { float dd = v[c] - mu; s2 += dd * dd; }
#pragma unroll
    for (int m = 32; m; m >>= 1) s2 += __shfl_xor(s2, m);
    float var = s2 * (1.0f / D_);
    float inv = 1.0f / sqrtf(var + 1e-5f);
    float u[16];
    float s3 = 0.f;
#pragma unroll
    for (int c = 0; c < 16; ++c) {
        int i = c * 64 + lane;
        u[c] = (v[c] - mu) * inv * lng[i] + lnb[i];
        s3 += u[c] * u[c];
    }
#pragma unroll
    for (int m = 32; m; m >>= 1) s3 += __shfl_xor(s3, m);
    float rn = 1.0f / (sqrtf(s3) + 1e-6f);
    float cacc = 0.f;
#pragma unroll
    for (int c = 0; c < 16; ++c) {
        int i = c * 64 + lane;
        float qv = u[c] * rn;
        qkb[(size_t)r * D_ + i] = f2bf(qv * kg[i]);
        cacc += qv * kb[i];
    }
#pragma unroll
    for (int m = 32; m; m >>= 1) cacc += __shfl_xor(cacc, m);
    if (lane == 0) cj[r] = cacc;
}

// ---------------------------------------------------------------------------
// K1: FUSED logits (bf16 MFMA) + softmax-dispatch + slot-partials.
// 512 threads (8 waves), 64 tokens/block, 512 blocks (2 blocks/CU).
// Round-19 changes vs round-18 (T12/m240): NO inline-asm cvt_pk — plain-C
// RNE f2bf lets the compiler schedule conversion VALU around loads/MFMA;
// wbuf staged once into LDS (8 KB) -> in-loop w reads are broadcast b128
// LDS reads instead of 64 global VMEM/thread.
// ---------------------------------------------------------------------------
__global__ __launch_bounds__(512) void k_fused(
    const float* __restrict__ x, const unsigned short* __restrict__ qkb,
    const float* __restrict__ wbuf, const float* __restrict__ cj,
    const float* __restrict__ s0p,
    float* __restrict__ lgbuf, float* __restrict__ spart)
{
    __shared__ float smem[6336];
    float* wsd  = smem;            // [2048]: w2[1024] | w1[1024]
    float* part = smem + 2048;     // [2 kh][64 tok][16 j] = 2048
    float* nrmp = smem + 4096;     // [2 kh][64 tok] = 128
    float* sums = smem + 4224;     // [64 tok][17] = 1088
    float* disp = smem + 5312;     // [64 tok][16] = 1024

    int tid = threadIdx.x;
    int tok0 = blockIdx.x * 64;
    int wv = tid >> 6;             // 0..7
    int lane = tid & 63;
    int wt = wv & 3;               // token tile
    int kh = wv >> 2;              // k half
    int am = lane & 15;            // A row (token) AND B row (j)
    int kgr = lane >> 4;           // k-group 0..3

    // one-time stage: wbuf -> LDS (512 threads x 1 float4)
    ((float4*)wsd)[tid] = ((const float4*)wbuf)[tid];
    __syncthreads();

    const float* xrow = x + (size_t)(tok0 + wt * 16 + am) * D_ + kh * 512 + kgr * 8;
    const unsigned short* qrow = qkb + (size_t)am * 1024 + kh * 512 + kgr * 8;
    const float* w2row = wsd + kh * 512 + kgr * 8;
    const float* w1row = wsd + 1024 + kh * 512 + kgr * 8;

    f32x4 acc = {0.f, 0.f, 0.f, 0.f};
    float nrm = 0.f;
#pragma unroll 2
    for (int ks = 0; ks < 16; ++ks) {
        int off = ks * 32;
        float4 a0  = *(const float4*)(xrow + off);
        float4 a1  = *(const float4*)(xrow + off + 4);
        float4 w2a = *(const float4*)(w2row + off);
        float4 w2b = *(const float4*)(w2row + off + 4);
        float4 w1a = *(const float4*)(w1row + off);
        float4 w1b = *(const float4*)(w1row + off + 4);
        nrm += (w2a.x * a0.x + w1a.x) * a0.x + (w2a.y * a0.y + w1a.y) * a0.y
             + (w2a.z * a0.z + w1a.z) * a0.z + (w2a.w * a0.w + w1a.w) * a0.w
             + (w2b.x * a1.x + w1b.x) * a1.x + (w2b.y * a1.y + w1b.y) * a1.y
             + (w2b.z * a1.z + w1b.z) * a1.z + (w2b.w * a1.w + w1b.w) * a1.w;
        union { unsigned short u[8]; short8_t s; } ua;
        ua.u[0] = f2bf(a0.x); ua.u[1] = f2bf(a0.y);
        ua.u[2] = f2bf(a0.z); ua.u[3] = f2bf(a0.w);
        ua.u[4] = f2bf(a1.x); ua.u[5] = f2bf(a1.y);
        ua.u[6] = f2bf(a1.z); ua.u[7] = f2bf(a1.w);
        short8_t bv = *(const short8_t*)(qrow + off);
        acc = __builtin_amdgcn_mfma_f32_16x16x32_bf16(ua.s, bv, acc, 0, 0, 0);
    }
    // norm: reduce across k-groups (lanes at xor 16, 32 share token am)
    nrm += __shfl_xor(nrm, 16);
    nrm += __shfl_xor(nrm, 32);

    // store per-k-half partials (C/D layout: col=am=j, row=kgr*4+r=token)
#pragma unroll
    for (int r = 0; r < 4; ++r)
        part[(kh * 64 + wt * 16 + kgr * 4 + r) * 16 + am] = acc[r];
    if (kgr == 0) nrmp[kh * 64 + wt * 16 + am] = nrm;
    __syncthreads();

    // merge k-halves -> sums + lgbuf
#pragma unroll
    for (int it = 0; it < 3; ++it) {
        int idx = tid + it * 512;
        if (idx < 1088) {
            int t = idx / 17, v = idx - t * 17;
            float sv = (v < 16) ? (part[t * 16 + v] + part[1024 + t * 16 + v])
                                : (nrmp[t] + nrmp[64 + t]);
            sums[idx] = sv;
            lgbuf[(size_t)(tok0 + t) * 20 + v] = sv;
        }
    }
    __syncthreads();

    // softmax-dispatch (entmax in k_epi): one thread per token
    if (tid < 64) {
        const float* sp = sums + tid * 17;
        float ss = sp[16] + wbuf[2048];
        float rn = 1.0f / (sqrtf(ss) + 1e-6f);
        float inv0 = 1.0f / s0p[0];
        float lg[16];
#pragma unroll
        for (int j = 0; j < 16; ++j) lg[j] = (sp[j] + cj[j]) * rn;
        float dsp[16];
#pragma unroll
        for (int sl = 0; sl < 2; ++sl) {
            float a[8], m = -1e30f;
#pragma unroll
            for (int ee = 0; ee < 8; ++ee) { a[ee] = lg[2 * ee + sl] * inv0; m = fmaxf(m, a[ee]); }
            float den = 0.f;
#pragma unroll
            for (int ee = 0; ee < 8; ++ee) { a[ee] = expf(a[ee] - m); den += a[ee]; }
            float r = 1.0f / den;
#pragma unroll
            for (int ee = 0; ee < 8; ++ee) dsp[2 * ee + sl] = a[ee] * r;
        }
#pragma unroll
        for (int q4i = 0; q4i < 4; ++q4i)
            *(float4*)(&disp[tid * 16 + q4i * 4]) =
                make_float4(dsp[q4i * 4 + 0], dsp[q4i * 4 + 1], dsp[q4i * 4 + 2], dsp[q4i * 4 + 3]);
    }
    __syncthreads();

    // phase 2: slot partials, J-HALF per thread-half (x L2-warm)
    int th = tid >> 8;             // 0/1: experts [th*8, th*8+8)
    int cix = tid & 255;           // float4 column of d
    const float* xp = x + (size_t)tok0 * D_ + cix * 4;
    float4 acc2[8];
#pragma unroll
    for (int j = 0; j < 8; ++j) { acc2[j].x = 0.f; acc2[j].y = 0.f; acc2[j].z = 0.f; acc2[j].w = 0.f; }
#pragma unroll 8
    for (int n = 0; n < 64; ++n) {
        float4 xv = *(const float4*)(xp + (size_t)n * D_);
        const float4* q4 = (const float4*)(disp + n * 16 + th * 8);
        float4 s0 = q4[0], s1 = q4[1];
        acc2[0].x += s0.x * xv.x; acc2[0].y += s0.x * xv.y; acc2[0].z += s0.x * xv.z; acc2[0].w += s0.x * xv.w;
        acc2[1].x += s0.y * xv.x; acc2[1].y += s0.y * xv.y; acc2[1].z += s0.y * xv.z; acc2[1].w += s0.y * xv.w;
        acc2[2].x += s0.z * xv.x; acc2[2].y += s0.z * xv.y; acc2[2].z += s0.z * xv.z; acc2[2].w += s0.z * xv.w;
        acc2[3].x += s0.w * xv.x; acc2[3].y += s0.w * xv.y; acc2[3].z += s0.w * xv.z; acc2[3].w += s0.w * xv.w;
        acc2[4].x += s1.x * xv.x; acc2[4].y += s1.x * xv.y; acc2[4].z += s1.x * xv.z; acc2[4].w += s1.x * xv.w;
        acc2[5].x += s1.y * xv.x; acc2[5].y += s1.y * xv.y; acc2[5].z += s1.y * xv.z; acc2[5].w += s1.y * xv.w;
        acc2[6].x += s1.z * xv.x; acc2[6].y += s1.z * xv.y; acc2[6].z += s1.z * xv.z; acc2[6].w += s1.z * xv.w;
        acc2[7].x += s1.w * xv.x; acc2[7].y += s1.w * xv.y; acc2[7].z += s1.w * xv.z; acc2[7].w += s1.w * xv.w;
    }
    float* op = spart + ((size_t)blockIdx.x * 16 + th * 8) * 1024 + cix * 4;
#pragma unroll
    for (int j = 0; j < 8; ++j)
        *(float4*)(op + (size_t)j * 1024) = acc2[j];
}

// ---------------------------------------------------------------------------
// K1b: per-token entmax15 epilogue -> combine only.
// ---------------------------------------------------------------------------
__global__ __launch_bounds__(64) void k_epi(
    const float* __restrict__ lgbuf, const float* __restrict__ cj,
    const float* __restrict__ wbuf, const float* __restrict__ s1p,
    float* __restrict__ combine)
{
    int tok = blockIdx.x * 64 + threadIdx.x;
    const float* lp = lgbuf + (size_t)tok * 20;
    float s[17];
    float4 q0 = *(const float4*)(lp + 0);
    float4 q1 = *(const float4*)(lp + 4);
    float4 q2 = *(const float4*)(lp + 8);
    float4 q3 = *(const float4*)(lp + 12);
    s[0] = q0.x; s[1] = q0.y; s[2] = q0.z; s[3] = q0.w;
    s[4] = q1.x; s[5] = q1.y; s[6] = q1.z; s[7] = q1.w;
    s[8] = q2.x; s[9] = q2.y; s[10] = q2.z; s[11] = q2.w;
    s[12] = q3.x; s[13] = q3.y; s[14] = q3.z; s[15] = q3.w;
    s[16] = lp[16];

    float ss = s[16] + wbuf[2048];
    float rn = 1.0f / (sqrtf(ss) + 1e-6f);
    float inv1h = 0.5f / s1p[0];
    float lg[16];
#pragma unroll
    for (int j = 0; j < 16; ++j) lg[j] = (s[j] + cj[j]) * rn;

    float z[16], zmax = -1e30f;
#pragma unroll
    for (int j = 0; j < 16; ++j) { z[j] = lg[j] * inv1h; zmax = fmaxf(zmax, z[j]); }
#pragma unroll
    for (int j = 0; j < 16; ++j) z[j] -= zmax;
    float zsr[16];
#pragma unroll
    for (int j = 0; j < 16; ++j) zsr[j] = z[j];
#pragma unroll
    for (int rr = 0; rr < 16; ++rr) {
#pragma unroll
        for (int jj = (rr & 1); jj + 1 < 16; jj += 2) {
            float aa = zsr[jj], bb = zsr[jj + 1];
            zsr[jj] = fmaxf(aa, bb);
            zsr[jj + 1] = fminf(aa, bb);
        }
    }
    float cs = 0.f, css = 0.f, tau_star = 0.f;
#pragma unroll
    for (int kk = 1; kk <= 16; ++kk) {
        cs += zsr[kk - 1];
        css += zsr[kk - 1] * zsr[kk - 1];
        float fk = (float)kk;
        float mean = cs / fk, msq = css / fk;
        float ssv = fk * (msq - mean * mean);
        float delta = fmaxf((1.0f - ssv) / fk, 1e-12f);
        float tau = mean - sqrtf(delta);
        tau_star = (tau <= zsr[kk - 1]) ? tau : tau_star;
    }
    float4* cw = (float4*)(combine + (size_t)tok * 16);
#pragma unroll
    for (int q4i = 0; q4i < 4; ++q4i) {
        float4 cv;
        float t0 = fmaxf(z[q4i * 4 + 0] - tau_star, 0.f);
        float t1 = fmaxf(z[q4i * 4 + 1] - tau_star, 0.f);
        float t2 = fmaxf(z[q4i * 4 + 2] - tau_star, 0.f);
        float t3 = fmaxf(z[q4i * 4 + 3] - tau_star, 0.f);
        cv.x = t0 * t0; cv.y = t1 * t1; cv.z = t2 * t2; cv.w = t3 * t3;
        cw[q4i] = cv;
    }
}

// ---------------------------------------------------------------------------
// K2c: coalesced reduce over 64 nc chunks. slotsT[e][k][t] (t=b*2+s, j=e*2+s).
// ---------------------------------------------------------------------------
__global__ __launch_bounds__(256) void k_slots_reduce(
    const float* __restrict__ spart, float* __restrict__ slotsT)
{
    int j = blockIdx.x, b = blockIdx.y;
    int tid = threadIdx.x;
    const float* p = spart + ((size_t)(b * 64) * 16 + j) * 1024 + tid * 4;
    float4 s; s.x = 0.f; s.y = 0.f; s.z = 0.f; s.w = 0.f;
#pragma unroll 8
    for (int nc = 0; nc < 64; ++nc) {
        float4 v = *(const float4*)(p + (size_t)nc * 16384);
        s.x += v.x; s.y += v.y; s.z += v.z; s.w += v.w;
    }
    int e = j >> 1, sl = j & 1;
    int t = b * 2 + sl;
    float* o = slotsT + ((size_t)e * 1024 + tid * 4) * 16 + t;
    o[0] = s.x; o[16] = s.y; o[32] = s.z; o[48] = s.w;
}

// ---------------------------------------------------------------------------
// D1: split-K h-partials. p1[ks=16][e][col=4096][t=16], K-chunk 64.
// ---------------------------------------------------------------------------
__global__ __launch_bounds__(256) void k_mlp1(
    const float* __restrict__ w1, const float* __restrict__ slotsT,
    float* __restrict__ p1)
{
    __shared__ float sm[1024];
    int cc = blockIdx.x, ks = blockIdx.y, e = blockIdx.z;
    int tid = threadIdx.x;
    int k0 = ks * 64;
    int col = cc * 1024 + tid * 4;
    ((float4*)sm)[tid] = ((const float4*)(slotsT + ((size_t)e * 1024 + k0) * 16))[tid];
    __syncthreads();

    const float* wp = w1 + (size_t)e * 1024 * 4096 + (size_t)k0 * 4096 + col;
    float4 acc[16];
#pragma unroll
    for (int t = 0; t < 16; ++t) { acc[t].x = 0.f; acc[t].y = 0.f; acc[t].z = 0.f; acc[t].w = 0.f; }
#pragma unroll 8
    for (int kk = 0; kk < 64; ++kk) {
        float4 w = *(const float4*)(wp + (size_t)kk * 4096);
        const float4* q4 = (const float4*)(sm + kk * 16);
        float4 s0 = q4[0], s1 = q4[1], s2 = q4[2], s3 = q4[3];
        acc[0].x  += s0.x * w.x; acc[0].y  += s0.x * w.y; acc[0].z  += s0.x * w.z; acc[0].w  += s0.x * w.w;
        acc[1].x  += s0.y * w.x; acc[1].y  += s0.y * w.y; acc[1].z  += s0.y * w.z; acc[1].w  += s0.y * w.w;
        acc[2].x  += s0.z * w.x; acc[2].y  += s0.z * w.y; acc[2].z  += s0.z * w.z; acc[2].w  += s0.z * w.w;
        acc[3].x  += s0.w * w.x; acc[3].y  += s0.w * w.y; acc[3].z  += s0.w * w.z; acc[3].w  += s0.w * w.w;
        acc[4].x  += s1.x * w.x; acc[4].y  += s1.x * w.y; acc[4].z  += s1.x * w.z; acc[4].w  += s1.x * w.w;
        acc[5].x  += s1.y * w.x; acc[5].y  += s1.y * w.y; acc[5].z  += s1.y * w.z; acc[5].w  += s1.y * w.w;
        acc[6].x  += s1.z * w.x; acc[6].y  += s1.z * w.y; acc[6].z  += s1.z * w.z; acc[6].w  += s1.z * w.w;
        acc[7].x  += s1.w * w.x; acc[7].y  += s1.w * w.y; acc[7].z  += s1.w * w.z; acc[7].w  += s1.w * w.w;
        acc[8].x  += s2.x * w.x; acc[8].y  += s2.x * w.y; acc[8].z  += s2.x * w.z; acc[8].w  += s2.x * w.w;
        acc[9].x  += s2.y * w.x; acc[9].y  += s2.y * w.y; acc[9].z  += s2.y * w.z; acc[9].w  += s2.y * w.w;
        acc[10].x += s2.z * w.x; acc[10].y += s2.z * w.y; acc[10].z += s2.z * w.z; acc[10].w += s2.z * w.w;
        acc[11].x += s2.w * w.x; acc[11].y += s2.w * w.y; acc[11].z += s2.w * w.z; acc[11].w += s2.w * w.w;
        acc[12].x += s3.x * w.x; acc[12].y += s3.x * w.y; acc[12].z += s3.x * w.z; acc[12].w += s3.x * w.w;
        acc[13].x += s3.y * w.x; acc[13].y += s3.y * w.y; acc[13].z += s3.y * w.z; acc[13].w += s3.y * w.w;
        acc[14].x += s3.z * w.x; acc[14].y += s3.z * w.y; acc[14].z += s3.z * w.z; acc[14].w += s3.z * w.w;
        acc[15].x += s3.w * w.x; acc[15].y += s3.w * w.y; acc[15].z += s3.w * w.z; acc[15].w += s3.w * w.w;
    }
    float av0[16], av1[16], av2[16], av3[16];
#pragma unroll
    for (int t = 0; t < 16; ++t) { av0[t] = acc[t].x; av1[t] = acc[t].y; av2[t] = acc[t].z; av3[t] = acc[t].w; }
    float* op = p1 + (((size_t)ks * 8 + e) * 4096 + col) * 16;
#pragma unroll
    for (int q = 0; q < 4; ++q) {
        *(float4*)(op + 0 * 16 + q * 4) = make_float4(av0[q*4+0], av0[q*4+1], av0[q*4+2], av0[q*4+3]);
        *(float4*)(op + 1 * 16 + q * 4) = make_float4(av1[q*4+0], av1[q*4+1], av1[q*4+2], av1[q*4+3]);
        *(float4*)(op + 2 * 16 + q * 4) = make_float4(av2[q*4+0], av2[q*4+1], av2[q*4+2], av2[q*4+3]);
        *(float4*)(op + 3 * 16 + q * 4) = make_float4(av3[q*4+0], av3[q*4+1], av3[q*4+2], av3[q*4+3]);
    }
}

// ---------------------------------------------------------------------------
// D2: fused {reduce p1 (16 chunks) + bias + gelu} -> LDS, then out-partials.
// p2[ks=64][e][col=1024][t=16], hidden-chunk 64. grid (64, 8) = 512 blocks.
// ---------------------------------------------------------------------------
__global__ __launch_bounds__(256) void k_mlp2f(
    const float* __restrict__ w2, const float* __restrict__ p1,
    const float* __restrict__ b1, float* __restrict__ p2)
{
    __shared__ float sm[1024];
    int ks = blockIdx.x, e = blockIdx.y;
    int tid = threadIdx.x;
    int k0 = ks * 64;                  // hidden-col chunk [k0, k0+64)
    int col = tid * 4;

    {
        int fidx = tid;
        const float* pp = p1 + (size_t)e * 65536 + (size_t)k0 * 16 + fidx * 4;
        float4 s; s.x = 0.f; s.y = 0.f; s.z = 0.f; s.w = 0.f;
#pragma unroll
        for (int ksp = 0; ksp < 16; ++ksp) {
            float4 v = *(const float4*)(pp + (size_t)ksp * 524288);
            s.x += v.x; s.y += v.y; s.z += v.z; s.w += v.w;
        }
        int colh = k0 + (fidx >> 2);
        float bb = b1[(size_t)e * 4096 + colh];
        s.x += bb; s.y += bb; s.z += bb; s.w += bb;
        s.x = 0.5f * s.x * (1.0f + erff(s.x * 0.70710678118654752f));
        s.y = 0.5f * s.y * (1.0f + erff(s.y * 0.70710678118654752f));
        s.z = 0.5f * s.z * (1.0f + erff(s.z * 0.70710678118654752f));
        s.w = 0.5f * s.w * (1.0f + erff(s.w * 0.70710678118654752f));
        *(float4*)(&sm[fidx * 4]) = s;
    }
    __syncthreads();

    const float* wp = w2 + (size_t)e * 4096 * 1024 + (size_t)k0 * 1024 + col;
    float4 acc[16];
#pragma unroll
    for (int t = 0; t < 16; ++t) { acc[t].x = 0.f; acc[t].y = 0.f; acc[t].z = 0.f; acc[t].w = 0.f; }
#pragma unroll 8
    for (int kk = 0; kk < 64; ++kk) {
        float4 w = *(const float4*)(wp + (size_t)kk * 1024);
        const float4* q4 = (const float4*)(sm + kk * 16);
        float4 s0 = q4[0], s1 = q4[1], s2 = q4[2], s3 = q4[3];
        acc[0].x  += s0.x * w.x; acc[0].y  += s0.x * w.y; acc[0].z  += s0.x * w.z; acc[0].w  += s0.x * w.w;
        acc[1].x  += s0.y * w.x; acc[1].y  += s0.y * w.y; acc[1].z  += s0.y * w.z; acc[1].w  += s0.y * w.w;
        acc[2].x  += s0.z * w.x; acc[2].y  += s0.z * w.y; acc[2].z  += s0.z * w.z; acc[2].w  += s0.z * w.w;
        acc[3].x  += s0.w * w.x; acc[3].y  += s0.w * w.y; acc[3].z  += s0.w * w.z; acc[3].w  += s0.w * w.w;
        acc[4].x  += s1.x * w.x; acc[4].y  += s1.x * w.y; acc[4].z  += s1.x * w.z; acc[4].w  += s1.x * w.w;
        acc[5].x  += s1.y * w.x; acc[5].y  += s1.y * w.y; acc[5].z  += s1.y * w.z; acc[5].w  += s1.y * w.w;
        acc[6].x  += s1.z * w.x; acc[6].y  += s1.z * w.y; acc[6].z  += s1.z * w.z; acc[6].w  += s1.z * w.w;
        acc[7].x  += s1.w * w.x; acc[7].y  += s1.w * w.y; acc[7].z  += s1.w * w.z; acc[7].w  += s1.w * w.w;
        acc[8].x  += s2.x * w.x; acc[8].y  += s2.x * w.y; acc[8].z  += s2.x * w.z; acc[8].w  += s2.x * w.w;
        acc[9].x  += s2.y * w.x; acc[9].y  += s2.y * w.y; acc[9].z  += s2.y * w.z; acc[9].w  += s2.y * w.w;
        acc[10].x += s2.z * w.x; acc[10].y += s2.z * w.y; acc[10].z += s2.z * w.z; acc[10].w += s2.z * w.w;
        acc[11].x += s2.w * w.x; acc[11].y += s2.w * w.y; acc[11].z += s2.w * w.z; acc[11].w += s2.w * w.w;
        acc[12].x += s3.x * w.x; acc[12].y += s3.x * w.y; acc[12].z += s3.x * w.z; acc[12].w += s3.x * w.w;
        acc[13].x += s3.y * w.x; acc[13].y += s3.y * w.y; acc[13].z += s3.y * w.z; acc[13].w += s3.y * w.w;
        acc[14].x += s3.z * w.x; acc[14].y += s3.z * w.y; acc[14].z += s3.z * w.z; acc[14].w += s3.z * w.w;
        acc[15].x += s3.w * w.x; acc[15].y += s3.w * w.y; acc[15].z += s3.w * w.z; acc[15].w += s3.w * w.w;
    }
    float av0[16], av1[16], av2[16], av3[16];
#pragma unroll
    for (int t = 0; t < 16; ++t) { av0[t] = acc[t].x; av1[t] = acc[t].y; av2[t] = acc[t].z; av3[t] = acc[t].w; }
    float* op = p2 + (((size_t)ks * 8 + e) * 1024 + col) * 16;
#pragma unroll
    for (int q = 0; q < 4; ++q) {
        *(float4*)(op + 0 * 16 + q * 4) = make_float4(av0[q*4+0], av0[q*4+1], av0[q*4+2], av0[q*4+3]);
        *(float4*)(op + 1 * 16 + q * 4) = make_float4(av1[q*4+0], av1[q*4+1], av1[q*4+2], av1[q*4+3]);
        *(float4*)(op + 2 * 16 + q * 4) = make_float4(av2[q*4+0], av2[q*4+1], av2[q*4+2], av2[q*4+3]);
        *(float4*)(op + 3 * 16 + q * 4) = make_float4(av3[q*4+0], av3[q*4+1], av3[q*4+2], av3[q*4+3]);
    }
}

// ---------------------------------------------------------------------------
// D2r: co[b][j][d] = Σ_ks p2 + b2 (64 ks chunks). 8192 elems x 4/thread.
// ---------------------------------------------------------------------------
__global__ __launch_bounds__(256) void k_red2(
    const float* __restrict__ p2, const float* __restrict__ b2,
    float* __restrict__ co)
{
    int idx = blockIdx.x * 256 + threadIdx.x;    // 0..32767
    int q = idx & 3, d = (idx >> 2) & 1023, e = idx >> 12;
    const float* p = p2 + ((size_t)e * 1024 + d) * 16 + q * 4;
    float4 s; s.x = 0.f; s.y = 0.f; s.z = 0.f; s.w = 0.f;
#pragma unroll 8
    for (int ks = 0; ks < 64; ++ks) {
        float4 v = *(const float4*)(p + (size_t)ks * 131072);
        s.x += v.x; s.y += v.y; s.z += v.z; s.w += v.w;
    }
    float bb = b2[(size_t)e * 1024 + d];
    float vv[4] = { s.x + bb, s.y + bb, s.z + bb, s.w + bb };
#pragma unroll
    for (int u = 0; u < 4; ++u) {
        int t = q * 4 + u;
        int b = t >> 1, sl = t & 1;
        co[((size_t)b * 16 + e * 2 + sl) * 1024 + d] = vv[u];
    }
}

// ---------------------------------------------------------------------------
// KE: out[b,n,:] = sum_j combine[b,n,j] * co[b][j][:]. Combine tile in LDS.
// ---------------------------------------------------------------------------
__global__ __launch_bounds__(256) void k_out(
    const float* __restrict__ co, const float* __restrict__ combine,
    float* __restrict__ out)
{
    __shared__ float sm[1024];
    int b = blockIdx.y, tile = blockIdx.x;     // 64 tokens per tile
    int tid = threadIdx.x;
    ((float4*)sm)[tid] = ((const float4*)(combine + ((size_t)b * N_ + tile * 64) * 16))[tid];
    float4 cv[16];
#pragma unroll
    for (int j = 0; j < 16; ++j)
        cv[j] = ((const float4*)(co + ((size_t)b * 16 + j) * 1024))[tid];
    __syncthreads();
    float4* ob = (float4*)(out + ((size_t)b * N_ + tile * 64) * 1024) + tid;
#pragma unroll 2
    for (int it = 0; it < 64; ++it) {
        const float* cm = sm + it * 16;
        float4 acc; acc.x = 0.f; acc.y = 0.f; acc.z = 0.f; acc.w = 0.f;
#pragma unroll
        for (int j = 0; j < 16; ++j) {
            float wj = cm[j];
            acc.x += wj * cv[j].x; acc.y += wj * cv[j].y;
            acc.z += wj * cv[j].z; acc.w += wj * cv[j].w;
        }
        ob[(size_t)it * 256] = acc;
    }
}

// ---------------------------------------------------------------------------
extern "C" void kernel_launch(void* const* d_in, const int* in_sizes, int n_in,
                              void* d_out, int out_size, void* d_ws, size_t ws_size,
                              hipStream_t stream)
{
    const float* x   = (const float*)d_in[0];
    const float* phi = (const float*)d_in[2];
    const float* kg  = (const float*)d_in[3];
    const float* kb  = (const float*)d_in[4];
    const float* qg  = (const float*)d_in[5];
    const float* qb  = (const float*)d_in[6];
    const float* lng = (const float*)d_in[7];
    const float* lnb = (const float*)d_in[8];
    const float* s0  = (const float*)d_in[9];
    const float* s1  = (const float*)d_in[10];
    const float* w1  = (const float*)d_in[11];
    const float* b1  = (const float*)d_in[12];
    const float* w2  = (const float*)d_in[13];
    const float* b2  = (const float*)d_in[14];
    // occ weights d_in[15..18]: provably dead (exact-zero combine/dispatch)

    float* out = (float*)d_out;
    float* ws  = (float*)d_ws;

    unsigned short* qkb = (unsigned short*)ws;   // 16384 shorts = 8192 floats
    float* cj       = ws + 8192;                 // 16
    float* wbuf     = cj + 16;                   // 2064
    float* combine  = wbuf + 2064;               // 524288
    float* slotsT   = combine + 524288;          // 131072
    float* co       = slotsT + 131072;           // 131072
    float* lgbuf    = co + 131072;               // 655360 (lives with spart)
    float* arenaA   = lgbuf + 655360;            // 8388608 (spart -> p1)
    float* arenaB   = arenaA + 8388608;          // 8388608 (p2)
    float* spart    = arenaA;
    float* p1       = arenaA;
    float* p2       = arenaB;

    k_prep        <<<dim3(17),        dim3(64),  0, stream>>>(phi, qg, qb, lng, lnb, kg, kb, qkb, cj, wbuf);
    k_fused       <<<dim3(512),       dim3(512), 0, stream>>>(x, qkb, wbuf, cj, s0, lgbuf, spart);
    k_epi         <<<dim3(512),       dim3(64),  0, stream>>>(lgbuf, cj, wbuf, s1, combine);
    k_slots_reduce<<<dim3(16, 8),     dim3(256), 0, stream>>>(spart, slotsT);
    k_mlp1        <<<dim3(4, 16, 8),  dim3(256), 0, stream>>>(w1, slotsT, p1);
    k_mlp2f       <<<dim3(64, 8),     dim3(256), 0, stream>>>(w2, p1, b1, p2);
    k_red2        <<<dim3(128),       dim3(256), 0, stream>>>(p2, b2, co);
    k_out         <<<dim3(64, 8),     dim3(256), 0, stream>>>(co, combine, out);
}